// Round 13
// baseline (206.619 us; speedup 1.0000x reference)
//
#include <hip/hip_runtime.h>

typedef short short8 __attribute__((ext_vector_type(8)));
typedef __bf16 bf16x8 __attribute__((ext_vector_type(8)));
typedef float f32x4 __attribute__((ext_vector_type(4)));
typedef short s16x4 __attribute__((ext_vector_type(4)));
typedef unsigned u32x4 __attribute__((ext_vector_type(4)));

__device__ __forceinline__ short f2bf(float f) {
  unsigned u = __builtin_bit_cast(unsigned, f);
  u = (u + 0x7FFFu + ((u >> 16) & 1u)) >> 16;
  return (short)u;
}
__device__ __forceinline__ f32x4 mfma16(short8 a, short8 b, f32x4 c) {
  return __builtin_amdgcn_mfma_f32_16x16x32_bf16(
      __builtin_bit_cast(bf16x8, a), __builtin_bit_cast(bf16x8, b), c, 0, 0, 0);
}
__device__ __forceinline__ float sigm(float x) { return 1.0f / (1.0f + __expf(-x)); }
__device__ __forceinline__ float ftanh(float x) {
  return 1.0f - 2.0f / (1.0f + __expf(2.0f * x));
}
__device__ __forceinline__ f32x4 ld4(const float* p) { return *(const f32x4*)p; }
__device__ __forceinline__ void ntst4(float* p, f32x4 v) {
  __builtin_nontemporal_store(v, (f32x4*)p);
}

// ---------------------------------------------------------------------------
// Weight pre-pack: f32 [CO][CI][3][3] -> bf16 [K/8][CO][8], K = tap*CI + ci.
// ---------------------------------------------------------------------------
__global__ void pack_w(const float* __restrict__ w1, const float* __restrict__ w2,
                       const float* __restrict__ w3, short* __restrict__ out) {
  int e = blockIdx.x * 256 + threadIdx.x;
  if (e < 46080) {
    int kb8 = e / 320, n = e % 320;
    short8 v;
#pragma unroll
    for (int j = 0; j < 8; ++j) {
      int k = kb8 * 8 + j;
      int tap = k >> 7, ci = k & 127;
      v[j] = f2bf(w1[(n * 128 + ci) * 9 + tap]);
    }
    *(short8*)&out[e * 8] = v;
    return;
  }
  e -= 46080;
  if (e < 13824) {
    int kb8 = e / 192, n = e % 192;
    short8 v;
#pragma unroll
    for (int j = 0; j < 8; ++j) {
      int k = kb8 * 8 + j;
      int tap = k >> 6, ci = k & 63;
      v[j] = f2bf(w2[(n * 64 + ci) * 9 + tap]);
    }
    *(short8*)&out[(46080 + e) * 8] = v;
    return;
  }
  e -= 13824;
  {
    int kb8 = e / 64, n = e % 64;
    short8 v;
#pragma unroll
    for (int j = 0; j < 8; ++j) {
      int k = kb8 * 8 + j;
      int tap = k >> 6, ci = k & 63;
      v[j] = f2bf(w3[(n * 64 + ci) * 9 + tap]);
    }
    *(short8*)&out[(46080 + 13824 + e) * 8] = v;
  }
}

// ===========================================================================
// R13 main path: R8 structure + LDS diet (25.7 KB) for 4 blocks/CU.
//   mid4_k [0..511]=attn: conv2 -> strided k7/v7 (R10-verified) -> q via
//     combf (comb free after conv2 barrier) -> sequential K-stream (R8) ->
//     softmax -> ws_wt.  [512..1023]=gate: conv1 -> c_cur strided reload ->
//     ct/oa strided stores (same [ch*64+p] layout tail reads).
//   tail_k: verbatim R8 (softmax weights in, V-stream + PV + conv3 + LN).
// ===========================================================================
__launch_bounds__(512, 8)
__global__ void mid4_k(const float* __restrict__ input, const float* __restrict__ h_cur,
                       const float* __restrict__ c_cur, const float* __restrict__ ck,
                       const int* __restrict__ amask,
                       const float* __restrict__ conv_b, const float* __restrict__ proj_b,
                       const float* __restrict__ pos_w, const float* __restrict__ pos_b,
                       const short* __restrict__ pk1, const short* __restrict__ pk2,
                       float* __restrict__ o_k, float* __restrict__ o_v,
                       float* __restrict__ ws_wt, float* __restrict__ ws_ct,
                       unsigned* __restrict__ ws_oa) {
  __shared__ short comb[12800];  // 25.6 KB total LDS (plus sc_lds)
  __shared__ float sc_lds[8];
  float* combf = (float*)comb;   // 6400 floats capacity; q uses 4160

  const int tid = threadIdx.x;
  const int wave = tid >> 6, lane = tid & 63;
  const int col = lane & 15, g4 = lane >> 4;
  const int wc = wave >> 1, wm = wave & 1;
  const int ch = wc * 16 + col;

  if (blockIdx.x < 512) {
    // ---------------- ATTENTION (conv2 + K-stream + softmax) ----------------
    const int b = blockIdx.x;
    if (tid < 8) sc_lds[tid] = 0.f;

    // stage input -> 64ch rotated bf16 tile
#pragma unroll
    for (int i = 0; i < 2; ++i) {
      int idx = (tid + 512 * i) * 4;
      int c = idx >> 6, p0 = idx & 63;
      f32x4 vi = ld4(&input[b * 4096 + idx]);
#pragma unroll
      for (int j = 0; j < 4; ++j) {
        int p = p0 + j;
        int pp = ((p >> 3) + 1) * 10 + (p & 7) + 1;
        comb[pp * 64 + ((c + pp * 8) & 63)] = f2bf(vi[j]);
      }
    }
    for (int i = tid; i < 2304; i += 512) {  // pad ring
      int pr = i >> 6, c = i & 63;
      int pp = (pr < 10) ? pr
               : (pr < 20) ? (80 + pr)
               : (pr < 28) ? ((pr - 19) * 10)
                           : ((pr - 27) * 10 + 9);
      comb[pp * 64 + c] = 0;
    }
    __syncthreads();

    // conv2: M=64 N=192 K=576
    f32x4 acc2[2][3];
#pragma unroll
    for (int m = 0; m < 2; ++m)
#pragma unroll
      for (int g = 0; g < 3; ++g) acc2[m][g] = (f32x4){0.f, 0.f, 0.f, 0.f};
    short8 bb2[3];
#pragma unroll
    for (int g = 0; g < 3; ++g)
      bb2[g] = *(const short8*)&pk2[((g4)*192 + g * 64 + ch) * 8];
    for (int s = 0; s < 18; ++s) {
      short8 bbn[3];
      if (s < 17) {
        int kb8 = (s + 1) * 4 + g4;
#pragma unroll
        for (int g = 0; g < 3; ++g)
          bbn[g] = *(const short8*)&pk2[(kb8 * 192 + g * 64 + ch) * 8];
      }
      int tap = s >> 1, cib = s & 1;
      int kh = tap / 3, kw = tap % 3;
      short8 a[2];
#pragma unroll
      for (int m = 0; m < 2; ++m) {
        int p = (wm * 2 + m) * 16 + col;
        int pp = ((p >> 3) + kh) * 10 + (p & 7) + kw;
        int slot = (cib * 32 + g4 * 8 + pp * 8) & 63;
        a[m] = *(const short8*)&comb[pp * 64 + slot];
      }
#pragma unroll
      for (int m = 0; m < 2; ++m)
#pragma unroll
        for (int g = 0; g < 3; ++g) acc2[m][g] = mfma16(a[m], bb2[g], acc2[m][g]);
      if (s < 17) {
#pragma unroll
        for (int g = 0; g < 3; ++g) bb2[g] = bbn[g];
      }
    }

    // epilogue: strided k7/v7 stores (R10-verified), q in regs, part7
    float qreg[8], part7 = 0.f;
    {
      float pb0 = proj_b[ch], pb1 = proj_b[64 + ch], pb2 = proj_b[128 + ch];
      const float rsq = 0.044194173824159216f;  // 1/sqrt(512)
      const size_t base7 = (size_t)(b * 8 + 7) * 4096;
#pragma unroll
      for (int m2 = 0; m2 < 2; ++m2) {
        int p0 = wm * 32 + m2 * 16 + g4 * 4;
        f32x4 pw7 = ld4(&pos_w[7 * 4096 + ch * 64 + p0]);
        f32x4 kq, vq;
#pragma unroll
        for (int r = 0; r < 4; ++r) {
          float kf = acc2[m2][0][r] + pb0 + pw7[r];
          float qf = (acc2[m2][1][r] + pb1) * rsq;
          float vf = acc2[m2][2][r] + pb2;
          kq[r] = kf;
          vq[r] = vf;
          qreg[m2 * 4 + r] = qf;
          part7 = fmaf(qf, kf, part7);
        }
        *(f32x4*)&o_k[base7 + ch * 64 + p0] = kq;
        *(f32x4*)&o_v[base7 + ch * 64 + p0] = vq;  // re-read by tail_k
      }
    }
    atomicAdd(&sc_lds[ch >> 3], part7);

    // hoist per-slot uniforms
    int msks[7];
    float pbv[7];
    const int hd = wave;
#pragma unroll
    for (int m = 0; m < 7; ++m) {
      msks[m] = amask[(b * 8 + hd) * 8 + m];
      pbv[m] = pos_b[m * 8 + hd];
    }

    __syncthreads();  // all conv2 comb reads done; atomics complete

    // q -> combf (comb reused; 4160 floats < 6400 capacity)
#pragma unroll
    for (int m2 = 0; m2 < 2; ++m2) {
      int p0 = wm * 32 + m2 * 16 + g4 * 4;
#pragma unroll
      for (int r = 0; r < 4; ++r) combf[ch * 65 + p0 + r] = qreg[m2 * 4 + r];
    }
    __syncthreads();

    const int d0 = lane * 4, d1 = (lane + 64) * 4;
    const int cs0 = d0 >> 6, po0 = d0 & 63, cs1 = d1 >> 6, po1 = d1 & 63;
    f32x4 q0, q1;
#pragma unroll
    for (int j = 0; j < 4; ++j) {
      q0[j] = combf[(hd * 8 + cs0) * 65 + po0 + j];
      q1[j] = combf[(hd * 8 + cs1) * 65 + po1 + j];
    }
    float sc7 = sc_lds[hd] + pos_b[7 * 8 + hd] + 5.0f;  // attn_mask_b

    // K-stream (R8's sequential form)
    float scv[8];
    scv[7] = sc7;
#pragma unroll
    for (int m = 0; m < 7; ++m) {
      const float* kp = ck + ((size_t)((b * 8 + m + 1) * 8 + hd)) * 512;
      const float* pw = pos_w + m * 4096 + hd * 512;
      f32x4 k0 = ld4(kp + d0) + ld4(pw + d0);
      f32x4 k1 = ld4(kp + d1) + ld4(pw + d1);
      float* dst = o_k + ((size_t)((b * 8 + m) * 8 + hd)) * 512;
      ntst4(dst + d0, k0);
      ntst4(dst + d1, k1);
      float part = 0.f;
#pragma unroll
      for (int j = 0; j < 4; ++j) {
        part = fmaf(q0[j], k0[j], part);
        part = fmaf(q1[j], k1[j], part);
      }
#pragma unroll
      for (int off = 32; off >= 1; off >>= 1) part += __shfl_xor(part, off);
      scv[m] = part + pbv[m] + (msks[m] ? -__builtin_inff() : 0.0f);
    }

    // softmax (redundant per lane), lane 0 writes
    float mx = scv[0];
#pragma unroll
    for (int m = 1; m < 8; ++m) mx = fmaxf(mx, scv[m]);
    float w[8], s = 0.f;
#pragma unroll
    for (int m = 0; m < 8; ++m) {
      w[m] = __expf(scv[m] - mx);
      s += w[m];
    }
    float inv = 1.0f / s;
    if (lane == 0) {
#pragma unroll
      for (int m = 0; m < 8; ++m)
        ws_wt[(size_t)b * 64 + hd * 8 + m] = w[m] * inv;
    }
  } else {
    // ---------------- GATE BLOCK (conv1, no LDS staging of c) ----------------
    const int b = blockIdx.x - 512;
#pragma unroll
    for (int i = 0; i < 2; ++i) {
      int idx = (tid + 512 * i) * 4;
      int c = idx >> 6, p0 = idx & 63;
      f32x4 vi = ld4(&input[b * 4096 + idx]);
      f32x4 vh = ld4(&h_cur[b * 4096 + idx]);
#pragma unroll
      for (int j = 0; j < 4; ++j) {
        int p = p0 + j;
        int pp = ((p >> 3) + 1) * 10 + (p & 7) + 1;
        comb[pp * 128 + ((c + pp * 8) & 127)] = f2bf(vi[j]);
        comb[pp * 128 + ((c + 64 + pp * 8) & 127)] = f2bf(vh[j]);
      }
    }
    for (int i = tid; i < 4608; i += 512) {  // pad ring
      int pr = i >> 7, c = i & 127;
      int pp = (pr < 10) ? pr
               : (pr < 20) ? (80 + pr)
               : (pr < 28) ? ((pr - 19) * 10)
                           : ((pr - 27) * 10 + 9);
      comb[pp * 128 + c] = 0;
    }
    __syncthreads();

    // conv1: M=64 N=320 K=1152
    f32x4 acc1[2][5];
#pragma unroll
    for (int m = 0; m < 2; ++m)
#pragma unroll
      for (int g = 0; g < 5; ++g) acc1[m][g] = (f32x4){0.f, 0.f, 0.f, 0.f};
    short8 bb1[5];
#pragma unroll
    for (int g = 0; g < 5; ++g)
      bb1[g] = *(const short8*)&pk1[((g4)*320 + g * 64 + ch) * 8];
    for (int s = 0; s < 36; ++s) {
      short8 bbn[5];
      if (s < 35) {
        int kb8 = (s + 1) * 4 + g4;
#pragma unroll
        for (int g = 0; g < 5; ++g)
          bbn[g] = *(const short8*)&pk1[(kb8 * 320 + g * 64 + ch) * 8];
      }
      int tap = s >> 2, cib = s & 3;
      int kh = tap / 3, kw = tap % 3;
      short8 a[2];
#pragma unroll
      for (int m = 0; m < 2; ++m) {
        int p = (wm * 2 + m) * 16 + col;
        int pp = ((p >> 3) + kh) * 10 + (p & 7) + kw;
        int slot = (cib * 32 + g4 * 8 + pp * 8) & 127;
        a[m] = *(const short8*)&comb[pp * 128 + slot];
      }
#pragma unroll
      for (int m = 0; m < 2; ++m)
#pragma unroll
        for (int g = 0; g < 5; ++g) acc1[m][g] = mfma16(a[m], bb1[g], acc1[m][g]);
      if (s < 35) {
#pragma unroll
        for (int g = 0; g < 5; ++g) bb1[g] = bbn[g];
      }
    }

    // epilogue: c_cur strided reload; ct/oa strided stores (layout [ch*64+p])
    {
      float bi0 = conv_b[ch], bi1 = conv_b[64 + ch], bi2 = conv_b[128 + ch];
      float bi3 = conv_b[192 + ch], bi4 = conv_b[256 + ch];
#pragma unroll
      for (int m2 = 0; m2 < 2; ++m2) {
        int p0 = wm * 32 + m2 * 16 + g4 * 4;
        f32x4 cr = ld4(&c_cur[(size_t)b * 4096 + ch * 64 + p0]);
        f32x4 cq;
        u32x4 oq;
#pragma unroll
        for (int r = 0; r < 4; ++r) {
          float iv = sigm(acc1[m2][0][r] + bi0);
          float fv = sigm(acc1[m2][1][r] + bi1);
          float ov = sigm(acc1[m2][2][r] + bi2);
          float gv = ftanh(acc1[m2][3][r] + bi3);
          float av = sigm(acc1[m2][4][r] + bi4);
          cq[r] = fv * cr[r] + iv * gv;
          oq[r] = ((unsigned)(unsigned short)f2bf(av) << 16) |
                  (unsigned)(unsigned short)f2bf(ov);
        }
        *(f32x4*)&ws_ct[(size_t)b * 4096 + ch * 64 + p0] = cq;
        *(u32x4*)&ws_oa[(size_t)b * 4096 + ch * 64 + p0] = oq;
      }
    }
  }
}

// ---------------------------------------------------------------------------
// tail_k: softmax weights in; V-stream + PV + conv3 + residual + LN + epilogue.
// (verbatim R8)
// ---------------------------------------------------------------------------
__launch_bounds__(512, 4)
__global__ void tail_k(const float* __restrict__ input, const float* __restrict__ cv,
                       const float* __restrict__ ws_wt,
                       const float* __restrict__ ws_ct,
                       const unsigned* __restrict__ ws_oa,
                       const float* __restrict__ out_b,
                       const float* __restrict__ ln_w, const float* __restrict__ ln_b,
                       const short* __restrict__ pk3,
                       float* __restrict__ o_h, float* __restrict__ o_c,
                       float* __restrict__ o_v) {
  __shared__ short comb[8320];
  __shared__ float Xb[4160];
  __shared__ float wt_s[64];
  __shared__ float red[16];
  float* combf = (float*)comb;
  unsigned* Xbu = (unsigned*)Xb;

  const int b = blockIdx.x;
  const int tid = threadIdx.x;
  const int wave = tid >> 6, lane = tid & 63;
  const int col = lane & 15, g4 = lane >> 4;
  const int wc = wave >> 1, wm = wave & 1;
  const int ch = wc * 16 + col;
  const int hd = wave;
  const int d0 = lane * 4, d1 = (lane + 64) * 4;

  f32x4 ctr[2];
  u32x4 oar[2];
#pragma unroll
  for (int i = 0; i < 2; ++i) {
    int idx = (tid + 512 * i) * 4;
    ctr[i] = ld4(&ws_ct[(size_t)b * 4096 + idx]);
    oar[i] = *(const u32x4*)&ws_oa[(size_t)b * 4096 + idx];
  }
  if (tid < 64) wt_s[tid] = ws_wt[(size_t)b * 64 + tid];

#pragma unroll
  for (int i = 0; i < 2; ++i) {
    int idx = (tid + 512 * i) * 4;
    int c = idx >> 6, p0 = idx & 63;
    f32x4 vi = ld4(&input[b * 4096 + idx]);
#pragma unroll
    for (int j = 0; j < 4; ++j) Xb[c * 65 + p0 + j] = vi[j];
  }
  for (int i = tid; i < 2304; i += 512) {  // pad ring
    int pr = i >> 6, c = i & 63;
    int pp = (pr < 10) ? pr
             : (pr < 20) ? (80 + pr)
             : (pr < 28) ? ((pr - 19) * 10)
                         : ((pr - 27) * 10 + 9);
    comb[pp * 64 + c] = 0;
  }
  __syncthreads();  // wt_s ready

  float wv[8];
#pragma unroll
  for (int m = 0; m < 8; ++m) wv[m] = wt_s[hd * 8 + m];

  f32x4 a0 = (f32x4){0.f, 0.f, 0.f, 0.f};
  f32x4 a1 = (f32x4){0.f, 0.f, 0.f, 0.f};
#pragma unroll
  for (int m = 0; m < 7; ++m) {
    const float* vp = cv + ((size_t)((b * 8 + m + 1) * 8 + hd)) * 512;
    f32x4 v0 = ld4(vp + d0);
    f32x4 v1 = ld4(vp + d1);
    float* dst = o_v + ((size_t)((b * 8 + m) * 8 + hd)) * 512;
    ntst4(dst + d0, v0);
    ntst4(dst + d1, v1);
    a0 += v0 * wv[m];
    a1 += v1 * wv[m];
  }
  {
    const float* vp = o_v + ((size_t)((b * 8 + 7) * 8 + hd)) * 512;
    a0 += ld4(vp + d0) * wv[7];
    a1 += ld4(vp + d1) * wv[7];
  }
#pragma unroll
  for (int j = 0; j < 4; ++j) {
    int dA = d0 + j, dB = d1 + j;
    int cA = hd * 8 + (dA >> 6), pA = dA & 63;
    int cB = hd * 8 + (dB >> 6), pB = dB & 63;
    int ppA = ((pA >> 3) + 1) * 10 + (pA & 7) + 1;
    int ppB = ((pB >> 3) + 1) * 10 + (pB & 7) + 1;
    comb[ppA * 64 + ((cA + ppA * 8) & 63)] = f2bf(a0[j]);
    comb[ppB * 64 + ((cB + ppB * 8) & 63)] = f2bf(a1[j]);
  }
  __syncthreads();

  // conv3: M=64 N=64 K=576
  f32x4 acc3[2];
  acc3[0] = (f32x4){0.f, 0.f, 0.f, 0.f};
  acc3[1] = (f32x4){0.f, 0.f, 0.f, 0.f};
  short8 bb3 = *(const short8*)&pk3[((g4)*64 + ch) * 8];
  for (int s = 0; s < 18; ++s) {
    short8 bbn;
    if (s < 17) {
      int kb8 = (s + 1) * 4 + g4;
      bbn = *(const short8*)&pk3[(kb8 * 64 + ch) * 8];
    }
    int tap = s >> 1, cib = s & 1;
    int kh = tap / 3, kw = tap % 3;
    short8 a[2];
#pragma unroll
    for (int m = 0; m < 2; ++m) {
      int p = (wm * 2 + m) * 16 + col;
      int pp = ((p >> 3) + kh) * 10 + (p & 7) + kw;
      int slot = (cib * 32 + g4 * 8 + pp * 8) & 63;
      a[m] = *(const short8*)&comb[pp * 64 + slot];
    }
#pragma unroll
    for (int m = 0; m < 2; ++m) acc3[m] = mfma16(a[m], bb3, acc3[m]);
    if (s < 17) bb3 = bbn;
  }

  float ov_[8], s1 = 0.f, s2 = 0.f;
  {
    float ob = out_b[ch];
#pragma unroll
    for (int m = 0; m < 2; ++m)
#pragma unroll
      for (int r = 0; r < 4; ++r) {
        int p = (wm * 2 + m) * 16 + g4 * 4 + r;
        float v = acc3[m][r] + ob + Xb[ch * 65 + p];
        ov_[m * 4 + r] = v;
        s1 += v;
        s2 += v * v;
      }
  }
#pragma unroll
  for (int off = 32; off >= 1; off >>= 1) {
    s1 += __shfl_xor(s1, off);
    s2 += __shfl_xor(s2, off);
  }
  if (lane == 0) { red[wave] = s1; red[8 + wave] = s2; }
  __syncthreads();
  float ts1 = 0.f, ts2 = 0.f;
#pragma unroll
  for (int w = 0; w < 8; ++w) { ts1 += red[w]; ts2 += red[8 + w]; }
  float mu = ts1 * (1.0f / 4096.0f);
  float var = ts2 * (1.0f / 4096.0f) - mu * mu;
  float rstd = rsqrtf(var + 1e-5f);

#pragma unroll
  for (int i = 0; i < 2; ++i) {
    int idx = (tid + 512 * i) * 4;
    int c = idx >> 6, p0 = idx & 63;
#pragma unroll
    for (int j = 0; j < 4; ++j) {
      combf[c * 65 + p0 + j] = ctr[i][j];
      Xbu[c * 65 + p0 + j] = oar[i][j];
    }
  }
  __syncthreads();

#pragma unroll
  for (int m = 0; m < 2; ++m)
#pragma unroll
    for (int r = 0; r < 4; ++r) {
      int p = (wm * 2 + m) * 16 + g4 * 4 + r;
      float ct = combf[ch * 65 + p];
      unsigned u = Xbu[ch * 65 + p];
      float og = __builtin_bit_cast(float, u << 16);
      float ag = __builtin_bit_cast(float, u & 0xffff0000u);
      float oln = (ov_[m * 4 + r] - mu) * rstd * ln_w[ch * 64 + p] + ln_b[ch * 64 + p];
      float cn = ct + ag * ftanh(oln);
      float hv = og * ftanh(cn);
      combf[ch * 65 + p] = hv;
      Xb[ch * 65 + p] = cn;
    }
  __syncthreads();
#pragma unroll
  for (int i = 0; i < 2; ++i) {
    int idx = (tid + 512 * i) * 4;
    int c = idx >> 6, p0 = idx & 63;
    f32x4 hq, cq;
#pragma unroll
    for (int j = 0; j < 4; ++j) {
      hq[j] = combf[c * 65 + p0 + j];
      cq[j] = Xb[c * 65 + p0 + j];
    }
    *(f32x4*)&o_h[b * 4096 + idx] = hq;
    *(f32x4*)&o_c[b * 4096 + idx] = cq;
  }
}

// ===========================================================================
// Fallback path (R3, proven): used only if ws_size < 32 MB.
// ===========================================================================
__launch_bounds__(512, 4)
__global__ void kqv_k(const float* __restrict__ input,
                      const float* __restrict__ proj_b,
                      const float* __restrict__ pos_w,
                      const short* __restrict__ pk2,
                      float* __restrict__ q_out, float* __restrict__ o_k,
                      float* __restrict__ o_v) {
  __shared__ short comb[6400];
  __shared__ float Xk[4160], Xq[4160], Xv[4160];
  const int b = blockIdx.x;
  const int tid = threadIdx.x;
  const int wave = tid >> 6, lane = tid & 63;
  const int col = lane & 15, g4 = lane >> 4;
  const int wc = wave >> 1, wm = wave & 1;
  const int ch = wc * 16 + col;
#pragma unroll
  for (int i = 0; i < 2; ++i) {
    int idx = (tid + 512 * i) * 4;
    int c = idx >> 6, p0 = idx & 63;
    f32x4 vi = ld4(&input[b * 4096 + idx]);
#pragma unroll
    for (int j = 0; j < 4; ++j) {
      int p = p0 + j;
      int pp = ((p >> 3) + 1) * 10 + (p & 7) + 1;
      comb[pp * 64 + ((c + pp * 8) & 63)] = f2bf(vi[j]);
    }
  }
  for (int i = tid; i < 2304; i += 512) {
    int pr = i >> 6, c = i & 63;
    int pp = (pr < 10) ? pr
             : (pr < 20) ? (80 + pr)
             : (pr < 28) ? ((pr - 19) * 10)
                         : ((pr - 27) * 10 + 9);
    comb[pp * 64 + c] = 0;
  }
  __syncthreads();
  f32x4 acc2[2][3];
#pragma unroll
  for (int m = 0; m < 2; ++m)
#pragma unroll
    for (int g = 0; g < 3; ++g) acc2[m][g] = (f32x4){0.f, 0.f, 0.f, 0.f};
  short8 bb2[3];
#pragma unroll
  for (int g = 0; g < 3; ++g)
    bb2[g] = *(const short8*)&pk2[((g4)*192 + g * 64 + ch) * 8];
  for (int s = 0; s < 18; ++s) {
    short8 bbn[3];
    if (s < 17) {
      int kb8 = (s + 1) * 4 + g4;
#pragma unroll
      for (int g = 0; g < 3; ++g)
        bbn[g] = *(const short8*)&pk2[(kb8 * 192 + g * 64 + ch) * 8];
    }
    int tap = s >> 1, cib = s & 1;
    int kh = tap / 3, kw = tap % 3;
    short8 a[2];
#pragma unroll
    for (int m = 0; m < 2; ++m) {
      int p = (wm * 2 + m) * 16 + col;
      int pp = ((p >> 3) + kh) * 10 + (p & 7) + kw;
      int slot = (cib * 32 + g4 * 8 + pp * 8) & 63;
      a[m] = *(const short8*)&comb[pp * 64 + slot];
    }
#pragma unroll
    for (int m = 0; m < 2; ++m)
#pragma unroll
      for (int g = 0; g < 3; ++g) acc2[m][g] = mfma16(a[m], bb2[g], acc2[m][g]);
    if (s < 17) {
#pragma unroll
      for (int g = 0; g < 3; ++g) bb2[g] = bbn[g];
    }
  }
  {
    float pb0 = proj_b[ch], pb1 = proj_b[64 + ch], pb2 = proj_b[128 + ch];
    const float rsq = 0.044194173824159216f;
#pragma unroll
    for (int m = 0; m < 2; ++m)
#pragma unroll
      for (int r = 0; r < 4; ++r) {
        int p = (wm * 2 + m) * 16 + g4 * 4 + r;
        Xk[ch * 65 + p] = acc2[m][0][r] + pb0 + pos_w[7 * 4096 + ch * 64 + p];
        Xq[ch * 65 + p] = (acc2[m][1][r] + pb1) * rsq;
        Xv[ch * 65 + p] = acc2[m][2][r] + pb2;
      }
  }
  __syncthreads();
  const size_t base7 = (size_t)(b * 64 + 56) * 512;
#pragma unroll
  for (int i = 0; i < 2; ++i) {
    int idx = (tid + 512 * i) * 4;
    int c = idx >> 6, p0 = idx & 63;
    f32x4 kq, qq, vq;
#pragma unroll
    for (int j = 0; j < 4; ++j) {
      kq[j] = Xk[c * 65 + p0 + j];
      qq[j] = Xq[c * 65 + p0 + j];
      vq[j] = Xv[c * 65 + p0 + j];
    }
    *(f32x4*)&o_k[base7 + idx] = kq;
    *(f32x4*)&q_out[(size_t)b * 4096 + idx] = qq;
    *(f32x4*)&o_v[base7 + idx] = vq;
  }
}

__launch_bounds__(64, 4)
__global__ void attn_k(const float* __restrict__ ck, const float* __restrict__ cv,
                       const int* __restrict__ amask,
                       const float* __restrict__ pos_w,
                       const float* __restrict__ pos_b,
                       const float* __restrict__ q_in,
                       float* __restrict__ o_k, float* __restrict__ o_v,
                       float* __restrict__ attn_out) {
  const int b = blockIdx.x >> 3;
  const int hd = blockIdx.x & 7;
  const int lane = threadIdx.x;
  const int d0 = lane * 4, d1 = (lane + 64) * 4;
  const float* qp = q_in + (size_t)b * 4096 + hd * 512;
  f32x4 q0 = ld4(qp + d0);
  f32x4 q1 = ld4(qp + d1);
  float sc[8];
#pragma unroll
  for (int m = 0; m < 7; ++m) {
    const float* kp = ck + ((size_t)((b * 8 + m + 1) * 8 + hd)) * 512;
    const float* pw = pos_w + m * 4096 + hd * 512;
    f32x4 k0 = ld4(kp + d0) + ld4(pw + d0);
    f32x4 k1 = ld4(kp + d1) + ld4(pw + d1);
    float* dst = o_k + ((size_t)((b * 8 + m) * 8 + hd)) * 512;
    ntst4(dst + d0, k0);
    ntst4(dst + d1, k1);
    float part = 0.f;
#pragma unroll
    for (int j = 0; j < 4; ++j) {
      part = fmaf(q0[j], k0[j], part);
      part = fmaf(q1[j], k1[j], part);
    }
#pragma unroll
    for (int off = 32; off >= 1; off >>= 1) part += __shfl_xor(part, off);
    float msk = amask[(b * 8 + hd) * 8 + m] ? -__builtin_inff() : 0.0f;
    sc[m] = part + pos_b[m * 8 + hd] + msk;
  }
  {
    const float* kp = o_k + ((size_t)((b * 8 + 7) * 8 + hd)) * 512;
    f32x4 k0 = ld4(kp + d0);
    f32x4 k1 = ld4(kp + d1);
    float part = 0.f;
#pragma unroll
    for (int j = 0; j < 4; ++j) {
      part = fmaf(q0[j], k0[j], part);
      part = fmaf(q1[j], k1[j], part);
    }
#pragma unroll
    for (int off = 32; off >= 1; off >>= 1) part += __shfl_xor(part, off);
    sc[7] = part + pos_b[7 * 8 + hd] + 5.0f;
  }
  float mx = sc[0];
#pragma unroll
  for (int m = 1; m < 8; ++m) mx = fmaxf(mx, sc[m]);
  float w[8], s = 0.f;
#pragma unroll
  for (int m = 0; m < 8; ++m) {
    w[m] = __expf(sc[m] - mx);
    s += w[m];
  }
  float inv = 1.0f / s;
#pragma unroll
  for (int m = 0; m < 8; ++m) w[m] *= inv;
  f32x4 a0 = (f32x4){0.f, 0.f, 0.f, 0.f};
  f32x4 a1 = (f32x4){0.f, 0.f, 0.f, 0.f};
#pragma unroll
  for (int m = 0; m < 7; ++m) {
    const float* vp = cv + ((size_t)((b * 8 + m + 1) * 8 + hd)) * 512;
    f32x4 v0 = ld4(vp + d0);
    f32x4 v1 = ld4(vp + d1);
    float* dst = o_v + ((size_t)((b * 8 + m) * 8 + hd)) * 512;
    ntst4(dst + d0, v0);
    ntst4(dst + d1, v1);
    a0 += v0 * w[m];
    a1 += v1 * w[m];
  }
  {
    const float* vp = o_v + ((size_t)((b * 8 + 7) * 8 + hd)) * 512;
    a0 += ld4(vp + d0) * w[7];
    a1 += ld4(vp + d1) * w[7];
  }
  float* ap = attn_out + (size_t)b * 4096 + hd * 512;
  *(f32x4*)&ap[d0] = a0;
  *(f32x4*)&ap[d1] = a1;
}

__launch_bounds__(512, 4)
__global__ void cell2_k(
    const float* __restrict__ input, const float* __restrict__ h_cur,
    const float* __restrict__ c_cur, const float* __restrict__ attn_in,
    const float* __restrict__ conv_b, const float* __restrict__ out_b,
    const float* __restrict__ ln_w, const float* __restrict__ ln_b,
    const short* __restrict__ pk1, const short* __restrict__ pk3,
    float* __restrict__ o_h, float* __restrict__ o_c) {
  __shared__ short comb[12800];
  __shared__ float Xb[4160];
  __shared__ float Qb[4160];
  __shared__ float Vb[4160];
  __shared__ float red[16];
  const int b = blockIdx.x;
  const int tid = threadIdx.x;
  const int wave = tid >> 6, lane = tid & 63;
  const int col = lane & 15, g4 = lane >> 4;
  const int wc = wave >> 1, wm = wave & 1;
  const int ch = wc * 16 + col;
#pragma unroll
  for (int i = 0; i < 2; ++i) {
    int idx = (tid + 512 * i) * 4;
    int c = idx >> 6, p0 = idx & 63;
    f32x4 vi = ld4(&input[b * 4096 + idx]);
    f32x4 vh = ld4(&h_cur[b * 4096 + idx]);
    f32x4 vc = ld4(&c_cur[b * 4096 + idx]);
#pragma unroll
    for (int j = 0; j < 4; ++j) {
      int p = p0 + j;
      int pp = ((p >> 3) + 1) * 10 + (p & 7) + 1;
      comb[pp * 128 + ((c + pp * 8) & 127)] = f2bf(vi[j]);
      comb[pp * 128 + ((c + 64 + pp * 8) & 127)] = f2bf(vh[j]);
      Xb[c * 65 + p] = vc[j];
    }
  }
  for (int i = tid; i < 4608; i += 512) {
    int pr = i >> 7, c = i & 127;
    int pp = (pr < 10) ? pr
             : (pr < 20) ? (80 + pr)
             : (pr < 28) ? ((pr - 19) * 10)
                         : ((pr - 27) * 10 + 9);
    comb[pp * 128 + c] = 0;
  }
  __syncthreads();
  f32x4 acc1[2][5];
#pragma unroll
  for (int m = 0; m < 2; ++m)
#pragma unroll
    for (int g = 0; g < 5; ++g) acc1[m][g] = (f32x4){0.f, 0.f, 0.f, 0.f};
  short8 bb1[5];
#pragma unroll
  for (int g = 0; g < 5; ++g)
    bb1[g] = *(const short8*)&pk1[((g4)*320 + g * 64 + ch) * 8];
  for (int s = 0; s < 36; ++s) {
    short8 bbn[5];
    if (s < 35) {
      int kb8 = (s + 1) * 4 + g4;
#pragma unroll
      for (int g = 0; g < 5; ++g)
        bbn[g] = *(const short8*)&pk1[(kb8 * 320 + g * 64 + ch) * 8];
    }
    int tap = s >> 2, cib = s & 3;
    int kh = tap / 3, kw = tap % 3;
    short8 a[2];
#pragma unroll
    for (int m = 0; m < 2; ++m) {
      int p = (wm * 2 + m) * 16 + col;
      int pp = ((p >> 3) + kh) * 10 + (p & 7) + kw;
      int slot = (cib * 32 + g4 * 8 + pp * 8) & 127;
      a[m] = *(const short8*)&comb[pp * 128 + slot];
    }
#pragma unroll
    for (int m = 0; m < 2; ++m)
#pragma unroll
      for (int g = 0; g < 5; ++g) acc1[m][g] = mfma16(a[m], bb1[g], acc1[m][g]);
    if (s < 35) {
#pragma unroll
      for (int g = 0; g < 5; ++g) bb1[g] = bbn[g];
    }
  }
  float ct_r[8], o_r[8], a_r[8];
  {
    float bi0 = conv_b[ch], bi1 = conv_b[64 + ch], bi2 = conv_b[128 + ch];
    float bi3 = conv_b[192 + ch], bi4 = conv_b[256 + ch];
#pragma unroll
    for (int m = 0; m < 2; ++m)
#pragma unroll
      for (int r = 0; r < 4; ++r) {
        int p = (wm * 2 + m) * 16 + g4 * 4 + r;
        float iv = sigm(acc1[m][0][r] + bi0);
        float fv = sigm(acc1[m][1][r] + bi1);
        float ov = sigm(acc1[m][2][r] + bi2);
        float gv = ftanh(acc1[m][3][r] + bi3);
        float av = sigm(acc1[m][4][r] + bi4);
        ct_r[m * 4 + r] = fv * Xb[ch * 65 + p] + iv * gv;
        o_r[m * 4 + r] = ov;
        a_r[m * 4 + r] = av;
      }
  }
  __syncthreads();
  {
    f32x4 av[2], iv[2];
#pragma unroll
    for (int i = 0; i < 2; ++i) {
      int idx = (tid + 512 * i) * 4;
      av[i] = ld4(&attn_in[b * 4096 + idx]);
      iv[i] = ld4(&input[b * 4096 + idx]);
    }
#pragma unroll
    for (int i = 0; i < 2; ++i) {
      int idx = (tid + 512 * i) * 4;
      int c = idx >> 6, p0 = idx & 63;
#pragma unroll
      for (int j = 0; j < 4; ++j) {
        int p = p0 + j;
        int pp = ((p >> 3) + 1) * 10 + (p & 7) + 1;
        comb[pp * 128 + ((c + pp * 8) & 127)] = f2bf(av[i][j]);
        Xb[c * 65 + p] = iv[i][j];
      }
    }
  }
  __syncthreads();
  f32x4 acc3[2];
  acc3[0] = (f32x4){0.f, 0.f, 0.f, 0.f};
  acc3[1] = (f32x4){0.f, 0.f, 0.f, 0.f};
  short8 bb3 = *(const short8*)&pk3[((g4)*64 + ch) * 8];
  for (int s = 0; s < 18; ++s) {
    short8 bbn;
    if (s < 17) {
      int kb8 = (s + 1) * 4 + g4;
      bbn = *(const short8*)&pk3[(kb8 * 64 + ch) * 8];
    }
    int tap = s >> 1, cib = s & 1;
    int kh = tap / 3, kw = tap % 3;
    short8 a[2];
#pragma unroll
    for (int m = 0; m < 2; ++m) {
      int p = (wm * 2 + m) * 16 + col;
      int pp = ((p >> 3) + kh) * 10 + (p & 7) + kw;
      int slot = (cib * 32 + g4 * 8 + pp * 8) & 127;
      a[m] = *(const short8*)&comb[pp * 128 + slot];
    }
#pragma unroll
    for (int m = 0; m < 2; ++m) acc3[m] = mfma16(a[m], bb3, acc3[m]);
    if (s < 17) bb3 = bbn;
  }
  float ov_[8], s1 = 0.f, s2 = 0.f;
  {
    float ob = out_b[ch];
#pragma unroll
    for (int m = 0; m < 2; ++m)
#pragma unroll
      for (int r = 0; r < 4; ++r) {
        int p = (wm * 2 + m) * 16 + g4 * 4 + r;
        float v = acc3[m][r] + ob + Xb[ch * 65 + p];
        ov_[m * 4 + r] = v;
        s1 += v;
        s2 += v * v;
      }
  }
#pragma unroll
  for (int off = 32; off >= 1; off >>= 1) {
    s1 += __shfl_xor(s1, off);
    s2 += __shfl_xor(s2, off);
  }
  if (lane == 0) { red[wave] = s1; red[8 + wave] = s2; }
  __syncthreads();
  float ts1 = 0.f, ts2 = 0.f;
#pragma unroll
  for (int w = 0; w < 8; ++w) { ts1 += red[w]; ts2 += red[8 + w]; }
  float mu = ts1 * (1.0f / 4096.0f);
  float var = ts2 * (1.0f / 4096.0f) - mu * mu;
  float rstd = rsqrtf(var + 1e-5f);
#pragma unroll
  for (int m = 0; m < 2; ++m)
#pragma unroll
    for (int r = 0; r < 4; ++r) {
      int p = (wm * 2 + m) * 16 + g4 * 4 + r;
      float oln = (ov_[m * 4 + r] - mu) * rstd * ln_w[ch * 64 + p] + ln_b[ch * 64 + p];
      float cn = ct_r[m * 4 + r] + a_r[m * 4 + r] * ftanh(oln);
      float hv = o_r[m * 4 + r] * ftanh(cn);
      Qb[ch * 65 + p] = hv;
      Vb[ch * 65 + p] = cn;
    }
  __syncthreads();
#pragma unroll
  for (int i = 0; i < 2; ++i) {
    int idx = (tid + 512 * i) * 4;
    int c = idx >> 6, p0 = idx & 63;
    f32x4 hv, cvv;
#pragma unroll
    for (int j = 0; j < 4; ++j) {
      hv[j] = Qb[c * 65 + p0 + j];
      cvv[j] = Vb[c * 65 + p0 + j];
    }
    *(f32x4*)&o_h[b * 4096 + idx] = hv;
    *(f32x4*)&o_c[b * 4096 + idx] = cvv;
  }
}

extern "C" void kernel_launch(void* const* d_in, const int* in_sizes, int n_in,
                              void* d_out, int out_size, void* d_ws, size_t ws_size,
                              hipStream_t stream) {
  (void)in_sizes; (void)n_in; (void)out_size;
  const float* input  = (const float*)d_in[0];
  const float* h_cur  = (const float*)d_in[1];
  const float* c_cur  = (const float*)d_in[2];
  const float* ck     = (const float*)d_in[3];
  const float* cv     = (const float*)d_in[4];
  const int*   amask  = (const int*)d_in[5];
  const float* conv_w = (const float*)d_in[6];
  const float* conv_b = (const float*)d_in[7];
  const float* proj_w = (const float*)d_in[8];
  const float* proj_b = (const float*)d_in[9];
  const float* out_w  = (const float*)d_in[10];
  const float* out_b  = (const float*)d_in[11];
  const float* ln_w   = (const float*)d_in[12];
  const float* ln_b   = (const float*)d_in[13];
  const float* pos_w  = (const float*)d_in[14];
  const float* pos_b  = (const float*)d_in[15];

  char* ws = (char*)d_ws;
  short* pk = (short*)ws;  // 1.03 MB
  float* o_h = (float*)d_out;
  float* o_c = o_h + 2097152;
  float* o_k = o_h + 4194304;
  float* o_v = o_h + 20971520;

  pack_w<<<252, 256, 0, stream>>>(conv_w, proj_w, out_w, pk);

  if (ws_size >= (32u << 20)) {
    float* ws_wt = (float*)(ws + (2u << 20));        // 131 KB softmax weights
    float* ws_ct = (float*)(ws + (16u << 20));       // 8 MB ct
    unsigned* ws_oa = (unsigned*)(ws + (24u << 20)); // 8 MB packed o,a
    mid4_k<<<1024, 512, 0, stream>>>(input, h_cur, c_cur, ck, amask,
                                     conv_b, proj_b, pos_w, pos_b,
                                     pk, pk + 368640,
                                     o_k, o_v, ws_wt, ws_ct, ws_oa);
    tail_k<<<512, 512, 0, stream>>>(input, cv, ws_wt, ws_ct, ws_oa,
                                    out_b, ln_w, ln_b, pk + 479232,
                                    o_h, o_c, o_v);
  } else {
    // fallback: proven R3 pipeline (scratch lives in d_out regions)
    kqv_k<<<512, 512, 0, stream>>>(input, proj_b, pos_w, pk + 368640,
                                   o_h, o_k, o_v);
    attn_k<<<4096, 64, 0, stream>>>(ck, cv, amask, pos_w, pos_b, o_h,
                                    o_k, o_v, o_c);
    cell2_k<<<512, 512, 0, stream>>>(input, h_cur, c_cur, o_c,
                                     conv_b, out_b, ln_w, ln_b,
                                     pk, pk + 479232, o_h, o_c);
  }
}

// Round 14
// 100.880 us; speedup vs baseline: 2.0482x; 2.0482x over previous
//
#include <hip/hip_runtime.h>

typedef short short8 __attribute__((ext_vector_type(8)));
typedef __bf16 bf16x8 __attribute__((ext_vector_type(8)));
typedef float f32x4 __attribute__((ext_vector_type(4)));
typedef short s16x4 __attribute__((ext_vector_type(4)));
typedef unsigned u32x4 __attribute__((ext_vector_type(4)));

__device__ __forceinline__ short f2bf(float f) {
  unsigned u = __builtin_bit_cast(unsigned, f);
  u = (u + 0x7FFFu + ((u >> 16) & 1u)) >> 16;
  return (short)u;
}
__device__ __forceinline__ f32x4 mfma16(short8 a, short8 b, f32x4 c) {
  return __builtin_amdgcn_mfma_f32_16x16x32_bf16(
      __builtin_bit_cast(bf16x8, a), __builtin_bit_cast(bf16x8, b), c, 0, 0, 0);
}
__device__ __forceinline__ float sigm(float x) { return 1.0f / (1.0f + __expf(-x)); }
__device__ __forceinline__ float ftanh(float x) {
  return 1.0f - 2.0f / (1.0f + __expf(2.0f * x));
}
__device__ __forceinline__ f32x4 ld4(const float* p) { return *(const f32x4*)p; }
__device__ __forceinline__ void ntst4(float* p, f32x4 v) {
  __builtin_nontemporal_store(v, (f32x4*)p);
}

// ---------------------------------------------------------------------------
// Weight pre-pack: f32 [CO][CI][3][3] -> bf16 [K/8][CO][8], K = tap*CI + ci.
// ---------------------------------------------------------------------------
__global__ void pack_w(const float* __restrict__ w1, const float* __restrict__ w2,
                       const float* __restrict__ w3, short* __restrict__ out) {
  int e = blockIdx.x * 256 + threadIdx.x;
  if (e < 46080) {
    int kb8 = e / 320, n = e % 320;
    short8 v;
#pragma unroll
    for (int j = 0; j < 8; ++j) {
      int k = kb8 * 8 + j;
      int tap = k >> 7, ci = k & 127;
      v[j] = f2bf(w1[(n * 128 + ci) * 9 + tap]);
    }
    *(short8*)&out[e * 8] = v;
    return;
  }
  e -= 46080;
  if (e < 13824) {
    int kb8 = e / 192, n = e % 192;
    short8 v;
#pragma unroll
    for (int j = 0; j < 8; ++j) {
      int k = kb8 * 8 + j;
      int tap = k >> 6, ci = k & 63;
      v[j] = f2bf(w2[(n * 64 + ci) * 9 + tap]);
    }
    *(short8*)&out[(46080 + e) * 8] = v;
    return;
  }
  e -= 13824;
  {
    int kb8 = e / 64, n = e % 64;
    short8 v;
#pragma unroll
    for (int j = 0; j < 8; ++j) {
      int k = kb8 * 8 + j;
      int tap = k >> 6, ci = k & 63;
      v[j] = f2bf(w3[(n * 64 + ci) * 9 + tap]);
    }
    *(short8*)&out[(46080 + 13824 + e) * 8] = v;
  }
}

// ===========================================================================
// R14 main path: R13 structure (25.5 KB LDS diet) with launch_bounds(512,4)
// — R13's (512,8) forced VGPR<=32 and collapsed ILP (206 µs). R8's identical
// code shape compiles to 60 VGPR under (512,4); at <=64 VGPR HW allows
// 8 waves/SIMD, and LDS now permits up to 6 blocks/CU -> target 4 blocks/CU.
//   mid4_k [0..511]=attn: conv2 -> strided k7/v7 -> q via combf -> K-stream
//     -> softmax -> ws_wt.  [512..1023]=gate: conv1 -> strided c_cur reload
//     -> ct/oa strided stores.
//   tail_k: verbatim R8 (softmax weights in, V-stream + PV + conv3 + LN).
// ===========================================================================
__launch_bounds__(512, 4)
__global__ void mid4_k(const float* __restrict__ input, const float* __restrict__ h_cur,
                       const float* __restrict__ c_cur, const float* __restrict__ ck,
                       const int* __restrict__ amask,
                       const float* __restrict__ conv_b, const float* __restrict__ proj_b,
                       const float* __restrict__ pos_w, const float* __restrict__ pos_b,
                       const short* __restrict__ pk1, const short* __restrict__ pk2,
                       float* __restrict__ o_k, float* __restrict__ o_v,
                       float* __restrict__ ws_wt, float* __restrict__ ws_ct,
                       unsigned* __restrict__ ws_oa) {
  __shared__ short comb[12800];  // 25.6 KB total LDS (plus sc_lds)
  __shared__ float sc_lds[8];
  float* combf = (float*)comb;   // 6400 floats capacity; q uses 4160

  const int tid = threadIdx.x;
  const int wave = tid >> 6, lane = tid & 63;
  const int col = lane & 15, g4 = lane >> 4;
  const int wc = wave >> 1, wm = wave & 1;
  const int ch = wc * 16 + col;

  if (blockIdx.x < 512) {
    // ---------------- ATTENTION (conv2 + K-stream + softmax) ----------------
    const int b = blockIdx.x;
    if (tid < 8) sc_lds[tid] = 0.f;

    // stage input -> 64ch rotated bf16 tile
#pragma unroll
    for (int i = 0; i < 2; ++i) {
      int idx = (tid + 512 * i) * 4;
      int c = idx >> 6, p0 = idx & 63;
      f32x4 vi = ld4(&input[b * 4096 + idx]);
#pragma unroll
      for (int j = 0; j < 4; ++j) {
        int p = p0 + j;
        int pp = ((p >> 3) + 1) * 10 + (p & 7) + 1;
        comb[pp * 64 + ((c + pp * 8) & 63)] = f2bf(vi[j]);
      }
    }
    for (int i = tid; i < 2304; i += 512) {  // pad ring
      int pr = i >> 6, c = i & 63;
      int pp = (pr < 10) ? pr
               : (pr < 20) ? (80 + pr)
               : (pr < 28) ? ((pr - 19) * 10)
                           : ((pr - 27) * 10 + 9);
      comb[pp * 64 + c] = 0;
    }
    __syncthreads();

    // conv2: M=64 N=192 K=576
    f32x4 acc2[2][3];
#pragma unroll
    for (int m = 0; m < 2; ++m)
#pragma unroll
      for (int g = 0; g < 3; ++g) acc2[m][g] = (f32x4){0.f, 0.f, 0.f, 0.f};
    short8 bb2[3];
#pragma unroll
    for (int g = 0; g < 3; ++g)
      bb2[g] = *(const short8*)&pk2[((g4)*192 + g * 64 + ch) * 8];
    for (int s = 0; s < 18; ++s) {
      short8 bbn[3];
      if (s < 17) {
        int kb8 = (s + 1) * 4 + g4;
#pragma unroll
        for (int g = 0; g < 3; ++g)
          bbn[g] = *(const short8*)&pk2[(kb8 * 192 + g * 64 + ch) * 8];
      }
      int tap = s >> 1, cib = s & 1;
      int kh = tap / 3, kw = tap % 3;
      short8 a[2];
#pragma unroll
      for (int m = 0; m < 2; ++m) {
        int p = (wm * 2 + m) * 16 + col;
        int pp = ((p >> 3) + kh) * 10 + (p & 7) + kw;
        int slot = (cib * 32 + g4 * 8 + pp * 8) & 63;
        a[m] = *(const short8*)&comb[pp * 64 + slot];
      }
#pragma unroll
      for (int m = 0; m < 2; ++m)
#pragma unroll
        for (int g = 0; g < 3; ++g) acc2[m][g] = mfma16(a[m], bb2[g], acc2[m][g]);
      if (s < 17) {
#pragma unroll
        for (int g = 0; g < 3; ++g) bb2[g] = bbn[g];
      }
    }

    // epilogue: strided k7/v7 stores (R10-verified), q in regs, part7
    float qreg[8], part7 = 0.f;
    {
      float pb0 = proj_b[ch], pb1 = proj_b[64 + ch], pb2 = proj_b[128 + ch];
      const float rsq = 0.044194173824159216f;  // 1/sqrt(512)
      const size_t base7 = (size_t)(b * 8 + 7) * 4096;
#pragma unroll
      for (int m2 = 0; m2 < 2; ++m2) {
        int p0 = wm * 32 + m2 * 16 + g4 * 4;
        f32x4 pw7 = ld4(&pos_w[7 * 4096 + ch * 64 + p0]);
        f32x4 kq, vq;
#pragma unroll
        for (int r = 0; r < 4; ++r) {
          float kf = acc2[m2][0][r] + pb0 + pw7[r];
          float qf = (acc2[m2][1][r] + pb1) * rsq;
          float vf = acc2[m2][2][r] + pb2;
          kq[r] = kf;
          vq[r] = vf;
          qreg[m2 * 4 + r] = qf;
          part7 = fmaf(qf, kf, part7);
        }
        *(f32x4*)&o_k[base7 + ch * 64 + p0] = kq;
        *(f32x4*)&o_v[base7 + ch * 64 + p0] = vq;  // re-read by tail_k
      }
    }
    atomicAdd(&sc_lds[ch >> 3], part7);

    // hoist per-slot uniforms
    int msks[7];
    float pbv[7];
    const int hd = wave;
#pragma unroll
    for (int m = 0; m < 7; ++m) {
      msks[m] = amask[(b * 8 + hd) * 8 + m];
      pbv[m] = pos_b[m * 8 + hd];
    }

    __syncthreads();  // all conv2 comb reads done; atomics complete

    // q -> combf (comb reused; 4160 floats < 6400 capacity)
#pragma unroll
    for (int m2 = 0; m2 < 2; ++m2) {
      int p0 = wm * 32 + m2 * 16 + g4 * 4;
#pragma unroll
      for (int r = 0; r < 4; ++r) combf[ch * 65 + p0 + r] = qreg[m2 * 4 + r];
    }
    __syncthreads();

    const int d0 = lane * 4, d1 = (lane + 64) * 4;
    const int cs0 = d0 >> 6, po0 = d0 & 63, cs1 = d1 >> 6, po1 = d1 & 63;
    f32x4 q0, q1;
#pragma unroll
    for (int j = 0; j < 4; ++j) {
      q0[j] = combf[(hd * 8 + cs0) * 65 + po0 + j];
      q1[j] = combf[(hd * 8 + cs1) * 65 + po1 + j];
    }
    float sc7 = sc_lds[hd] + pos_b[7 * 8 + hd] + 5.0f;  // attn_mask_b

    // K-stream (R8's sequential form)
    float scv[8];
    scv[7] = sc7;
#pragma unroll
    for (int m = 0; m < 7; ++m) {
      const float* kp = ck + ((size_t)((b * 8 + m + 1) * 8 + hd)) * 512;
      const float* pw = pos_w + m * 4096 + hd * 512;
      f32x4 k0 = ld4(kp + d0) + ld4(pw + d0);
      f32x4 k1 = ld4(kp + d1) + ld4(pw + d1);
      float* dst = o_k + ((size_t)((b * 8 + m) * 8 + hd)) * 512;
      ntst4(dst + d0, k0);
      ntst4(dst + d1, k1);
      float part = 0.f;
#pragma unroll
      for (int j = 0; j < 4; ++j) {
        part = fmaf(q0[j], k0[j], part);
        part = fmaf(q1[j], k1[j], part);
      }
#pragma unroll
      for (int off = 32; off >= 1; off >>= 1) part += __shfl_xor(part, off);
      scv[m] = part + pbv[m] + (msks[m] ? -__builtin_inff() : 0.0f);
    }

    // softmax (redundant per lane), lane 0 writes
    float mx = scv[0];
#pragma unroll
    for (int m = 1; m < 8; ++m) mx = fmaxf(mx, scv[m]);
    float w[8], s = 0.f;
#pragma unroll
    for (int m = 0; m < 8; ++m) {
      w[m] = __expf(scv[m] - mx);
      s += w[m];
    }
    float inv = 1.0f / s;
    if (lane == 0) {
#pragma unroll
      for (int m = 0; m < 8; ++m)
        ws_wt[(size_t)b * 64 + hd * 8 + m] = w[m] * inv;
    }
  } else {
    // ---------------- GATE BLOCK (conv1, no LDS staging of c) ----------------
    const int b = blockIdx.x - 512;
#pragma unroll
    for (int i = 0; i < 2; ++i) {
      int idx = (tid + 512 * i) * 4;
      int c = idx >> 6, p0 = idx & 63;
      f32x4 vi = ld4(&input[b * 4096 + idx]);
      f32x4 vh = ld4(&h_cur[b * 4096 + idx]);
#pragma unroll
      for (int j = 0; j < 4; ++j) {
        int p = p0 + j;
        int pp = ((p >> 3) + 1) * 10 + (p & 7) + 1;
        comb[pp * 128 + ((c + pp * 8) & 127)] = f2bf(vi[j]);
        comb[pp * 128 + ((c + 64 + pp * 8) & 127)] = f2bf(vh[j]);
      }
    }
    for (int i = tid; i < 4608; i += 512) {  // pad ring
      int pr = i >> 7, c = i & 127;
      int pp = (pr < 10) ? pr
               : (pr < 20) ? (80 + pr)
               : (pr < 28) ? ((pr - 19) * 10)
                           : ((pr - 27) * 10 + 9);
      comb[pp * 128 + c] = 0;
    }
    __syncthreads();

    // conv1: M=64 N=320 K=1152
    f32x4 acc1[2][5];
#pragma unroll
    for (int m = 0; m < 2; ++m)
#pragma unroll
      for (int g = 0; g < 5; ++g) acc1[m][g] = (f32x4){0.f, 0.f, 0.f, 0.f};
    short8 bb1[5];
#pragma unroll
    for (int g = 0; g < 5; ++g)
      bb1[g] = *(const short8*)&pk1[((g4)*320 + g * 64 + ch) * 8];
    for (int s = 0; s < 36; ++s) {
      short8 bbn[5];
      if (s < 35) {
        int kb8 = (s + 1) * 4 + g4;
#pragma unroll
        for (int g = 0; g < 5; ++g)
          bbn[g] = *(const short8*)&pk1[(kb8 * 320 + g * 64 + ch) * 8];
      }
      int tap = s >> 2, cib = s & 3;
      int kh = tap / 3, kw = tap % 3;
      short8 a[2];
#pragma unroll
      for (int m = 0; m < 2; ++m) {
        int p = (wm * 2 + m) * 16 + col;
        int pp = ((p >> 3) + kh) * 10 + (p & 7) + kw;
        int slot = (cib * 32 + g4 * 8 + pp * 8) & 127;
        a[m] = *(const short8*)&comb[pp * 128 + slot];
      }
#pragma unroll
      for (int m = 0; m < 2; ++m)
#pragma unroll
        for (int g = 0; g < 5; ++g) acc1[m][g] = mfma16(a[m], bb1[g], acc1[m][g]);
      if (s < 35) {
#pragma unroll
        for (int g = 0; g < 5; ++g) bb1[g] = bbn[g];
      }
    }

    // epilogue: c_cur strided reload; ct/oa strided stores (layout [ch*64+p])
    {
      float bi0 = conv_b[ch], bi1 = conv_b[64 + ch], bi2 = conv_b[128 + ch];
      float bi3 = conv_b[192 + ch], bi4 = conv_b[256 + ch];
#pragma unroll
      for (int m2 = 0; m2 < 2; ++m2) {
        int p0 = wm * 32 + m2 * 16 + g4 * 4;
        f32x4 cr = ld4(&c_cur[(size_t)b * 4096 + ch * 64 + p0]);
        f32x4 cq;
        u32x4 oq;
#pragma unroll
        for (int r = 0; r < 4; ++r) {
          float iv = sigm(acc1[m2][0][r] + bi0);
          float fv = sigm(acc1[m2][1][r] + bi1);
          float ov = sigm(acc1[m2][2][r] + bi2);
          float gv = ftanh(acc1[m2][3][r] + bi3);
          float av = sigm(acc1[m2][4][r] + bi4);
          cq[r] = fv * cr[r] + iv * gv;
          oq[r] = ((unsigned)(unsigned short)f2bf(av) << 16) |
                  (unsigned)(unsigned short)f2bf(ov);
        }
        *(f32x4*)&ws_ct[(size_t)b * 4096 + ch * 64 + p0] = cq;
        *(u32x4*)&ws_oa[(size_t)b * 4096 + ch * 64 + p0] = oq;
      }
    }
  }
}

// ---------------------------------------------------------------------------
// tail_k: softmax weights in; V-stream + PV + conv3 + residual + LN + epilogue.
// (verbatim R8)
// ---------------------------------------------------------------------------
__launch_bounds__(512, 4)
__global__ void tail_k(const float* __restrict__ input, const float* __restrict__ cv,
                       const float* __restrict__ ws_wt,
                       const float* __restrict__ ws_ct,
                       const unsigned* __restrict__ ws_oa,
                       const float* __restrict__ out_b,
                       const float* __restrict__ ln_w, const float* __restrict__ ln_b,
                       const short* __restrict__ pk3,
                       float* __restrict__ o_h, float* __restrict__ o_c,
                       float* __restrict__ o_v) {
  __shared__ short comb[8320];
  __shared__ float Xb[4160];
  __shared__ float wt_s[64];
  __shared__ float red[16];
  float* combf = (float*)comb;
  unsigned* Xbu = (unsigned*)Xb;

  const int b = blockIdx.x;
  const int tid = threadIdx.x;
  const int wave = tid >> 6, lane = tid & 63;
  const int col = lane & 15, g4 = lane >> 4;
  const int wc = wave >> 1, wm = wave & 1;
  const int ch = wc * 16 + col;
  const int hd = wave;
  const int d0 = lane * 4, d1 = (lane + 64) * 4;

  f32x4 ctr[2];
  u32x4 oar[2];
#pragma unroll
  for (int i = 0; i < 2; ++i) {
    int idx = (tid + 512 * i) * 4;
    ctr[i] = ld4(&ws_ct[(size_t)b * 4096 + idx]);
    oar[i] = *(const u32x4*)&ws_oa[(size_t)b * 4096 + idx];
  }
  if (tid < 64) wt_s[tid] = ws_wt[(size_t)b * 64 + tid];

#pragma unroll
  for (int i = 0; i < 2; ++i) {
    int idx = (tid + 512 * i) * 4;
    int c = idx >> 6, p0 = idx & 63;
    f32x4 vi = ld4(&input[b * 4096 + idx]);
#pragma unroll
    for (int j = 0; j < 4; ++j) Xb[c * 65 + p0 + j] = vi[j];
  }
  for (int i = tid; i < 2304; i += 512) {  // pad ring
    int pr = i >> 6, c = i & 63;
    int pp = (pr < 10) ? pr
             : (pr < 20) ? (80 + pr)
             : (pr < 28) ? ((pr - 19) * 10)
                         : ((pr - 27) * 10 + 9);
    comb[pp * 64 + c] = 0;
  }
  __syncthreads();  // wt_s ready

  float wv[8];
#pragma unroll
  for (int m = 0; m < 8; ++m) wv[m] = wt_s[hd * 8 + m];

  f32x4 a0 = (f32x4){0.f, 0.f, 0.f, 0.f};
  f32x4 a1 = (f32x4){0.f, 0.f, 0.f, 0.f};
#pragma unroll
  for (int m = 0; m < 7; ++m) {
    const float* vp = cv + ((size_t)((b * 8 + m + 1) * 8 + hd)) * 512;
    f32x4 v0 = ld4(vp + d0);
    f32x4 v1 = ld4(vp + d1);
    float* dst = o_v + ((size_t)((b * 8 + m) * 8 + hd)) * 512;
    ntst4(dst + d0, v0);
    ntst4(dst + d1, v1);
    a0 += v0 * wv[m];
    a1 += v1 * wv[m];
  }
  {
    const float* vp = o_v + ((size_t)((b * 8 + 7) * 8 + hd)) * 512;
    a0 += ld4(vp + d0) * wv[7];
    a1 += ld4(vp + d1) * wv[7];
  }
#pragma unroll
  for (int j = 0; j < 4; ++j) {
    int dA = d0 + j, dB = d1 + j;
    int cA = hd * 8 + (dA >> 6), pA = dA & 63;
    int cB = hd * 8 + (dB >> 6), pB = dB & 63;
    int ppA = ((pA >> 3) + 1) * 10 + (pA & 7) + 1;
    int ppB = ((pB >> 3) + 1) * 10 + (pB & 7) + 1;
    comb[ppA * 64 + ((cA + ppA * 8) & 63)] = f2bf(a0[j]);
    comb[ppB * 64 + ((cB + ppB * 8) & 63)] = f2bf(a1[j]);
  }
  __syncthreads();

  // conv3: M=64 N=64 K=576
  f32x4 acc3[2];
  acc3[0] = (f32x4){0.f, 0.f, 0.f, 0.f};
  acc3[1] = (f32x4){0.f, 0.f, 0.f, 0.f};
  short8 bb3 = *(const short8*)&pk3[((g4)*64 + ch) * 8];
  for (int s = 0; s < 18; ++s) {
    short8 bbn;
    if (s < 17) {
      int kb8 = (s + 1) * 4 + g4;
      bbn = *(const short8*)&pk3[(kb8 * 64 + ch) * 8];
    }
    int tap = s >> 1, cib = s & 1;
    int kh = tap / 3, kw = tap % 3;
    short8 a[2];
#pragma unroll
    for (int m = 0; m < 2; ++m) {
      int p = (wm * 2 + m) * 16 + col;
      int pp = ((p >> 3) + kh) * 10 + (p & 7) + kw;
      int slot = (cib * 32 + g4 * 8 + pp * 8) & 63;
      a[m] = *(const short8*)&comb[pp * 64 + slot];
    }
#pragma unroll
    for (int m = 0; m < 2; ++m) acc3[m] = mfma16(a[m], bb3, acc3[m]);
    if (s < 17) bb3 = bbn;
  }

  float ov_[8], s1 = 0.f, s2 = 0.f;
  {
    float ob = out_b[ch];
#pragma unroll
    for (int m = 0; m < 2; ++m)
#pragma unroll
      for (int r = 0; r < 4; ++r) {
        int p = (wm * 2 + m) * 16 + g4 * 4 + r;
        float v = acc3[m][r] + ob + Xb[ch * 65 + p];
        ov_[m * 4 + r] = v;
        s1 += v;
        s2 += v * v;
      }
  }
#pragma unroll
  for (int off = 32; off >= 1; off >>= 1) {
    s1 += __shfl_xor(s1, off);
    s2 += __shfl_xor(s2, off);
  }
  if (lane == 0) { red[wave] = s1; red[8 + wave] = s2; }
  __syncthreads();
  float ts1 = 0.f, ts2 = 0.f;
#pragma unroll
  for (int w = 0; w < 8; ++w) { ts1 += red[w]; ts2 += red[8 + w]; }
  float mu = ts1 * (1.0f / 4096.0f);
  float var = ts2 * (1.0f / 4096.0f) - mu * mu;
  float rstd = rsqrtf(var + 1e-5f);

#pragma unroll
  for (int i = 0; i < 2; ++i) {
    int idx = (tid + 512 * i) * 4;
    int c = idx >> 6, p0 = idx & 63;
#pragma unroll
    for (int j = 0; j < 4; ++j) {
      combf[c * 65 + p0 + j] = ctr[i][j];
      Xbu[c * 65 + p0 + j] = oar[i][j];
    }
  }
  __syncthreads();

#pragma unroll
  for (int m = 0; m < 2; ++m)
#pragma unroll
    for (int r = 0; r < 4; ++r) {
      int p = (wm * 2 + m) * 16 + g4 * 4 + r;
      float ct = combf[ch * 65 + p];
      unsigned u = Xbu[ch * 65 + p];
      float og = __builtin_bit_cast(float, u << 16);
      float ag = __builtin_bit_cast(float, u & 0xffff0000u);
      float oln = (ov_[m * 4 + r] - mu) * rstd * ln_w[ch * 64 + p] + ln_b[ch * 64 + p];
      float cn = ct + ag * ftanh(oln);
      float hv = og * ftanh(cn);
      combf[ch * 65 + p] = hv;
      Xb[ch * 65 + p] = cn;
    }
  __syncthreads();
#pragma unroll
  for (int i = 0; i < 2; ++i) {
    int idx = (tid + 512 * i) * 4;
    int c = idx >> 6, p0 = idx & 63;
    f32x4 hq, cq;
#pragma unroll
    for (int j = 0; j < 4; ++j) {
      hq[j] = combf[c * 65 + p0 + j];
      cq[j] = Xb[c * 65 + p0 + j];
    }
    *(f32x4*)&o_h[b * 4096 + idx] = hq;
    *(f32x4*)&o_c[b * 4096 + idx] = cq;
  }
}

// ===========================================================================
// Fallback path (R3, proven): used only if ws_size < 32 MB.
// ===========================================================================
__launch_bounds__(512, 4)
__global__ void kqv_k(const float* __restrict__ input,
                      const float* __restrict__ proj_b,
                      const float* __restrict__ pos_w,
                      const short* __restrict__ pk2,
                      float* __restrict__ q_out, float* __restrict__ o_k,
                      float* __restrict__ o_v) {
  __shared__ short comb[6400];
  __shared__ float Xk[4160], Xq[4160], Xv[4160];
  const int b = blockIdx.x;
  const int tid = threadIdx.x;
  const int wave = tid >> 6, lane = tid & 63;
  const int col = lane & 15, g4 = lane >> 4;
  const int wc = wave >> 1, wm = wave & 1;
  const int ch = wc * 16 + col;
#pragma unroll
  for (int i = 0; i < 2; ++i) {
    int idx = (tid + 512 * i) * 4;
    int c = idx >> 6, p0 = idx & 63;
    f32x4 vi = ld4(&input[b * 4096 + idx]);
#pragma unroll
    for (int j = 0; j < 4; ++j) {
      int p = p0 + j;
      int pp = ((p >> 3) + 1) * 10 + (p & 7) + 1;
      comb[pp * 64 + ((c + pp * 8) & 63)] = f2bf(vi[j]);
    }
  }
  for (int i = tid; i < 2304; i += 512) {
    int pr = i >> 6, c = i & 63;
    int pp = (pr < 10) ? pr
             : (pr < 20) ? (80 + pr)
             : (pr < 28) ? ((pr - 19) * 10)
                         : ((pr - 27) * 10 + 9);
    comb[pp * 64 + c] = 0;
  }
  __syncthreads();
  f32x4 acc2[2][3];
#pragma unroll
  for (int m = 0; m < 2; ++m)
#pragma unroll
    for (int g = 0; g < 3; ++g) acc2[m][g] = (f32x4){0.f, 0.f, 0.f, 0.f};
  short8 bb2[3];
#pragma unroll
  for (int g = 0; g < 3; ++g)
    bb2[g] = *(const short8*)&pk2[((g4)*192 + g * 64 + ch) * 8];
  for (int s = 0; s < 18; ++s) {
    short8 bbn[3];
    if (s < 17) {
      int kb8 = (s + 1) * 4 + g4;
#pragma unroll
      for (int g = 0; g < 3; ++g)
        bbn[g] = *(const short8*)&pk2[(kb8 * 192 + g * 64 + ch) * 8];
    }
    int tap = s >> 1, cib = s & 1;
    int kh = tap / 3, kw = tap % 3;
    short8 a[2];
#pragma unroll
    for (int m = 0; m < 2; ++m) {
      int p = (wm * 2 + m) * 16 + col;
      int pp = ((p >> 3) + kh) * 10 + (p & 7) + kw;
      int slot = (cib * 32 + g4 * 8 + pp * 8) & 63;
      a[m] = *(const short8*)&comb[pp * 64 + slot];
    }
#pragma unroll
    for (int m = 0; m < 2; ++m)
#pragma unroll
      for (int g = 0; g < 3; ++g) acc2[m][g] = mfma16(a[m], bb2[g], acc2[m][g]);
    if (s < 17) {
#pragma unroll
      for (int g = 0; g < 3; ++g) bb2[g] = bbn[g];
    }
  }
  {
    float pb0 = proj_b[ch], pb1 = proj_b[64 + ch], pb2 = proj_b[128 + ch];
    const float rsq = 0.044194173824159216f;
#pragma unroll
    for (int m = 0; m < 2; ++m)
#pragma unroll
      for (int r = 0; r < 4; ++r) {
        int p = (wm * 2 + m) * 16 + g4 * 4 + r;
        Xk[ch * 65 + p] = acc2[m][0][r] + pb0 + pos_w[7 * 4096 + ch * 64 + p];
        Xq[ch * 65 + p] = (acc2[m][1][r] + pb1) * rsq;
        Xv[ch * 65 + p] = acc2[m][2][r] + pb2;
      }
  }
  __syncthreads();
  const size_t base7 = (size_t)(b * 64 + 56) * 512;
#pragma unroll
  for (int i = 0; i < 2; ++i) {
    int idx = (tid + 512 * i) * 4;
    int c = idx >> 6, p0 = idx & 63;
    f32x4 kq, qq, vq;
#pragma unroll
    for (int j = 0; j < 4; ++j) {
      kq[j] = Xk[c * 65 + p0 + j];
      qq[j] = Xq[c * 65 + p0 + j];
      vq[j] = Xv[c * 65 + p0 + j];
    }
    *(f32x4*)&o_k[base7 + idx] = kq;
    *(f32x4*)&q_out[(size_t)b * 4096 + idx] = qq;
    *(f32x4*)&o_v[base7 + idx] = vq;
  }
}

__launch_bounds__(64, 4)
__global__ void attn_k(const float* __restrict__ ck, const float* __restrict__ cv,
                       const int* __restrict__ amask,
                       const float* __restrict__ pos_w,
                       const float* __restrict__ pos_b,
                       const float* __restrict__ q_in,
                       float* __restrict__ o_k, float* __restrict__ o_v,
                       float* __restrict__ attn_out) {
  const int b = blockIdx.x >> 3;
  const int hd = blockIdx.x & 7;
  const int lane = threadIdx.x;
  const int d0 = lane * 4, d1 = (lane + 64) * 4;
  const float* qp = q_in + (size_t)b * 4096 + hd * 512;
  f32x4 q0 = ld4(qp + d0);
  f32x4 q1 = ld4(qp + d1);
  float sc[8];
#pragma unroll
  for (int m = 0; m < 7; ++m) {
    const float* kp = ck + ((size_t)((b * 8 + m + 1) * 8 + hd)) * 512;
    const float* pw = pos_w + m * 4096 + hd * 512;
    f32x4 k0 = ld4(kp + d0) + ld4(pw + d0);
    f32x4 k1 = ld4(kp + d1) + ld4(pw + d1);
    float* dst = o_k + ((size_t)((b * 8 + m) * 8 + hd)) * 512;
    ntst4(dst + d0, k0);
    ntst4(dst + d1, k1);
    float part = 0.f;
#pragma unroll
    for (int j = 0; j < 4; ++j) {
      part = fmaf(q0[j], k0[j], part);
      part = fmaf(q1[j], k1[j], part);
    }
#pragma unroll
    for (int off = 32; off >= 1; off >>= 1) part += __shfl_xor(part, off);
    float msk = amask[(b * 8 + hd) * 8 + m] ? -__builtin_inff() : 0.0f;
    sc[m] = part + pos_b[m * 8 + hd] + msk;
  }
  {
    const float* kp = o_k + ((size_t)((b * 8 + 7) * 8 + hd)) * 512;
    f32x4 k0 = ld4(kp + d0);
    f32x4 k1 = ld4(kp + d1);
    float part = 0.f;
#pragma unroll
    for (int j = 0; j < 4; ++j) {
      part = fmaf(q0[j], k0[j], part);
      part = fmaf(q1[j], k1[j], part);
    }
#pragma unroll
    for (int off = 32; off >= 1; off >>= 1) part += __shfl_xor(part, off);
    sc[7] = part + pos_b[7 * 8 + hd] + 5.0f;
  }
  float mx = sc[0];
#pragma unroll
  for (int m = 1; m < 8; ++m) mx = fmaxf(mx, sc[m]);
  float w[8], s = 0.f;
#pragma unroll
  for (int m = 0; m < 8; ++m) {
    w[m] = __expf(sc[m] - mx);
    s += w[m];
  }
  float inv = 1.0f / s;
#pragma unroll
  for (int m = 0; m < 8; ++m) w[m] *= inv;
  f32x4 a0 = (f32x4){0.f, 0.f, 0.f, 0.f};
  f32x4 a1 = (f32x4){0.f, 0.f, 0.f, 0.f};
#pragma unroll
  for (int m = 0; m < 7; ++m) {
    const float* vp = cv + ((size_t)((b * 8 + m + 1) * 8 + hd)) * 512;
    f32x4 v0 = ld4(vp + d0);
    f32x4 v1 = ld4(vp + d1);
    float* dst = o_v + ((size_t)((b * 8 + m) * 8 + hd)) * 512;
    ntst4(dst + d0, v0);
    ntst4(dst + d1, v1);
    a0 += v0 * w[m];
    a1 += v1 * w[m];
  }
  {
    const float* vp = o_v + ((size_t)((b * 8 + 7) * 8 + hd)) * 512;
    a0 += ld4(vp + d0) * w[7];
    a1 += ld4(vp + d1) * w[7];
  }
  float* ap = attn_out + (size_t)b * 4096 + hd * 512;
  *(f32x4*)&ap[d0] = a0;
  *(f32x4*)&ap[d1] = a1;
}

__launch_bounds__(512, 4)
__global__ void cell2_k(
    const float* __restrict__ input, const float* __restrict__ h_cur,
    const float* __restrict__ c_cur, const float* __restrict__ attn_in,
    const float* __restrict__ conv_b, const float* __restrict__ out_b,
    const float* __restrict__ ln_w, const float* __restrict__ ln_b,
    const short* __restrict__ pk1, const short* __restrict__ pk3,
    float* __restrict__ o_h, float* __restrict__ o_c) {
  __shared__ short comb[12800];
  __shared__ float Xb[4160];
  __shared__ float Qb[4160];
  __shared__ float Vb[4160];
  __shared__ float red[16];
  const int b = blockIdx.x;
  const int tid = threadIdx.x;
  const int wave = tid >> 6, lane = tid & 63;
  const int col = lane & 15, g4 = lane >> 4;
  const int wc = wave >> 1, wm = wave & 1;
  const int ch = wc * 16 + col;
#pragma unroll
  for (int i = 0; i < 2; ++i) {
    int idx = (tid + 512 * i) * 4;
    int c = idx >> 6, p0 = idx & 63;
    f32x4 vi = ld4(&input[b * 4096 + idx]);
    f32x4 vh = ld4(&h_cur[b * 4096 + idx]);
    f32x4 vc = ld4(&c_cur[b * 4096 + idx]);
#pragma unroll
    for (int j = 0; j < 4; ++j) {
      int p = p0 + j;
      int pp = ((p >> 3) + 1) * 10 + (p & 7) + 1;
      comb[pp * 128 + ((c + pp * 8) & 127)] = f2bf(vi[j]);
      comb[pp * 128 + ((c + 64 + pp * 8) & 127)] = f2bf(vh[j]);
      Xb[c * 65 + p] = vc[j];
    }
  }
  for (int i = tid; i < 4608; i += 512) {
    int pr = i >> 7, c = i & 127;
    int pp = (pr < 10) ? pr
             : (pr < 20) ? (80 + pr)
             : (pr < 28) ? ((pr - 19) * 10)
                         : ((pr - 27) * 10 + 9);
    comb[pp * 128 + c] = 0;
  }
  __syncthreads();
  f32x4 acc1[2][5];
#pragma unroll
  for (int m = 0; m < 2; ++m)
#pragma unroll
    for (int g = 0; g < 5; ++g) acc1[m][g] = (f32x4){0.f, 0.f, 0.f, 0.f};
  short8 bb1[5];
#pragma unroll
  for (int g = 0; g < 5; ++g)
    bb1[g] = *(const short8*)&pk1[((g4)*320 + g * 64 + ch) * 8];
  for (int s = 0; s < 36; ++s) {
    short8 bbn[5];
    if (s < 35) {
      int kb8 = (s + 1) * 4 + g4;
#pragma unroll
      for (int g = 0; g < 5; ++g)
        bbn[g] = *(const short8*)&pk1[(kb8 * 320 + g * 64 + ch) * 8];
    }
    int tap = s >> 2, cib = s & 3;
    int kh = tap / 3, kw = tap % 3;
    short8 a[2];
#pragma unroll
    for (int m = 0; m < 2; ++m) {
      int p = (wm * 2 + m) * 16 + col;
      int pp = ((p >> 3) + kh) * 10 + (p & 7) + kw;
      int slot = (cib * 32 + g4 * 8 + pp * 8) & 127;
      a[m] = *(const short8*)&comb[pp * 128 + slot];
    }
#pragma unroll
    for (int m = 0; m < 2; ++m)
#pragma unroll
      for (int g = 0; g < 5; ++g) acc1[m][g] = mfma16(a[m], bb1[g], acc1[m][g]);
    if (s < 35) {
#pragma unroll
      for (int g = 0; g < 5; ++g) bb1[g] = bbn[g];
    }
  }
  float ct_r[8], o_r[8], a_r[8];
  {
    float bi0 = conv_b[ch], bi1 = conv_b[64 + ch], bi2 = conv_b[128 + ch];
    float bi3 = conv_b[192 + ch], bi4 = conv_b[256 + ch];
#pragma unroll
    for (int m = 0; m < 2; ++m)
#pragma unroll
      for (int r = 0; r < 4; ++r) {
        int p = (wm * 2 + m) * 16 + g4 * 4 + r;
        float iv = sigm(acc1[m][0][r] + bi0);
        float fv = sigm(acc1[m][1][r] + bi1);
        float ov = sigm(acc1[m][2][r] + bi2);
        float gv = ftanh(acc1[m][3][r] + bi3);
        float av = sigm(acc1[m][4][r] + bi4);
        ct_r[m * 4 + r] = fv * Xb[ch * 65 + p] + iv * gv;
        o_r[m * 4 + r] = ov;
        a_r[m * 4 + r] = av;
      }
  }
  __syncthreads();
  {
    f32x4 av[2], iv[2];
#pragma unroll
    for (int i = 0; i < 2; ++i) {
      int idx = (tid + 512 * i) * 4;
      av[i] = ld4(&attn_in[b * 4096 + idx]);
      iv[i] = ld4(&input[b * 4096 + idx]);
    }
#pragma unroll
    for (int i = 0; i < 2; ++i) {
      int idx = (tid + 512 * i) * 4;
      int c = idx >> 6, p0 = idx & 63;
#pragma unroll
      for (int j = 0; j < 4; ++j) {
        int p = p0 + j;
        int pp = ((p >> 3) + 1) * 10 + (p & 7) + 1;
        comb[pp * 128 + ((c + pp * 8) & 127)] = f2bf(av[i][j]);
        Xb[c * 65 + p] = iv[i][j];
      }
    }
  }
  __syncthreads();
  f32x4 acc3[2];
  acc3[0] = (f32x4){0.f, 0.f, 0.f, 0.f};
  acc3[1] = (f32x4){0.f, 0.f, 0.f, 0.f};
  short8 bb3 = *(const short8*)&pk3[((g4)*64 + ch) * 8];
  for (int s = 0; s < 18; ++s) {
    short8 bbn;
    if (s < 17) {
      int kb8 = (s + 1) * 4 + g4;
      bbn = *(const short8*)&pk3[(kb8 * 64 + ch) * 8];
    }
    int tap = s >> 1, cib = s & 1;
    int kh = tap / 3, kw = tap % 3;
    short8 a[2];
#pragma unroll
    for (int m = 0; m < 2; ++m) {
      int p = (wm * 2 + m) * 16 + col;
      int pp = ((p >> 3) + kh) * 10 + (p & 7) + kw;
      int slot = (cib * 32 + g4 * 8 + pp * 8) & 127;
      a[m] = *(const short8*)&comb[pp * 128 + slot];
    }
#pragma unroll
    for (int m = 0; m < 2; ++m) acc3[m] = mfma16(a[m], bb3, acc3[m]);
    if (s < 17) bb3 = bbn;
  }
  float ov_[8], s1 = 0.f, s2 = 0.f;
  {
    float ob = out_b[ch];
#pragma unroll
    for (int m = 0; m < 2; ++m)
#pragma unroll
      for (int r = 0; r < 4; ++r) {
        int p = (wm * 2 + m) * 16 + g4 * 4 + r;
        float v = acc3[m][r] + ob + Xb[ch * 65 + p];
        ov_[m * 4 + r] = v;
        s1 += v;
        s2 += v * v;
      }
  }
#pragma unroll
  for (int off = 32; off >= 1; off >>= 1) {
    s1 += __shfl_xor(s1, off);
    s2 += __shfl_xor(s2, off);
  }
  if (lane == 0) { red[wave] = s1; red[8 + wave] = s2; }
  __syncthreads();
  float ts1 = 0.f, ts2 = 0.f;
#pragma unroll
  for (int w = 0; w < 8; ++w) { ts1 += red[w]; ts2 += red[8 + w]; }
  float mu = ts1 * (1.0f / 4096.0f);
  float var = ts2 * (1.0f / 4096.0f) - mu * mu;
  float rstd = rsqrtf(var + 1e-5f);
#pragma unroll
  for (int m = 0; m < 2; ++m)
#pragma unroll
    for (int r = 0; r < 4; ++r) {
      int p = (wm * 2 + m) * 16 + g4 * 4 + r;
      float oln = (ov_[m * 4 + r] - mu) * rstd * ln_w[ch * 64 + p] + ln_b[ch * 64 + p];
      float cn = ct_r[m * 4 + r] + a_r[m * 4 + r] * ftanh(oln);
      float hv = o_r[m * 4 + r] * ftanh(cn);
      Qb[ch * 65 + p] = hv;
      Vb[ch * 65 + p] = cn;
    }
  __syncthreads();
#pragma unroll
  for (int i = 0; i < 2; ++i) {
    int idx = (tid + 512 * i) * 4;
    int c = idx >> 6, p0 = idx & 63;
    f32x4 hv, cvv;
#pragma unroll
    for (int j = 0; j < 4; ++j) {
      hv[j] = Qb[c * 65 + p0 + j];
      cvv[j] = Vb[c * 65 + p0 + j];
    }
    *(f32x4*)&o_h[b * 4096 + idx] = hv;
    *(f32x4*)&o_c[b * 4096 + idx] = cvv;
  }
}

extern "C" void kernel_launch(void* const* d_in, const int* in_sizes, int n_in,
                              void* d_out, int out_size, void* d_ws, size_t ws_size,
                              hipStream_t stream) {
  (void)in_sizes; (void)n_in; (void)out_size;
  const float* input  = (const float*)d_in[0];
  const float* h_cur  = (const float*)d_in[1];
  const float* c_cur  = (const float*)d_in[2];
  const float* ck     = (const float*)d_in[3];
  const float* cv     = (const float*)d_in[4];
  const int*   amask  = (const int*)d_in[5];
  const float* conv_w = (const float*)d_in[6];
  const float* conv_b = (const float*)d_in[7];
  const float* proj_w = (const float*)d_in[8];
  const float* proj_b = (const float*)d_in[9];
  const float* out_w  = (const float*)d_in[10];
  const float* out_b  = (const float*)d_in[11];
  const float* ln_w   = (const float*)d_in[12];
  const float* ln_b   = (const float*)d_in[13];
  const float* pos_w  = (const float*)d_in[14];
  const float* pos_b  = (const float*)d_in[15];

  char* ws = (char*)d_ws;
  short* pk = (short*)ws;  // 1.03 MB
  float* o_h = (float*)d_out;
  float* o_c = o_h + 2097152;
  float* o_k = o_h + 4194304;
  float* o_v = o_h + 20971520;

  pack_w<<<252, 256, 0, stream>>>(conv_w, proj_w, out_w, pk);

  if (ws_size >= (32u << 20)) {
    float* ws_wt = (float*)(ws + (2u << 20));        // 131 KB softmax weights
    float* ws_ct = (float*)(ws + (16u << 20));       // 8 MB ct
    unsigned* ws_oa = (unsigned*)(ws + (24u << 20)); // 8 MB packed o,a
    mid4_k<<<1024, 512, 0, stream>>>(input, h_cur, c_cur, ck, amask,
                                     conv_b, proj_b, pos_w, pos_b,
                                     pk, pk + 368640,
                                     o_k, o_v, ws_wt, ws_ct, ws_oa);
    tail_k<<<512, 512, 0, stream>>>(input, cv, ws_wt, ws_ct, ws_oa,
                                    out_b, ln_w, ln_b, pk + 479232,
                                    o_h, o_c, o_v);
  } else {
    // fallback: proven R3 pipeline (scratch lives in d_out regions)
    kqv_k<<<512, 512, 0, stream>>>(input, proj_b, pos_w, pk + 368640,
                                   o_h, o_k, o_v);
    attn_k<<<4096, 64, 0, stream>>>(ck, cv, amask, pos_w, pos_b, o_h,
                                    o_k, o_v, o_c);
    cell2_k<<<512, 512, 0, stream>>>(input, h_cur, c_cur, o_c,
                                     conv_b, out_b, ln_w, ln_b,
                                     pk, pk + 479232, o_h, o_c);
  }
}

// Round 15
// 99.991 us; speedup vs baseline: 2.0664x; 1.0089x over previous
//
#include <hip/hip_runtime.h>

typedef short short8 __attribute__((ext_vector_type(8)));
typedef __bf16 bf16x8 __attribute__((ext_vector_type(8)));
typedef float f32x4 __attribute__((ext_vector_type(4)));
typedef short s16x4 __attribute__((ext_vector_type(4)));
typedef unsigned u32x4 __attribute__((ext_vector_type(4)));

__device__ __forceinline__ short f2bf(float f) {
  unsigned u = __builtin_bit_cast(unsigned, f);
  u = (u + 0x7FFFu + ((u >> 16) & 1u)) >> 16;
  return (short)u;
}
__device__ __forceinline__ f32x4 mfma16(short8 a, short8 b, f32x4 c) {
  return __builtin_amdgcn_mfma_f32_16x16x32_bf16(
      __builtin_bit_cast(bf16x8, a), __builtin_bit_cast(bf16x8, b), c, 0, 0, 0);
}
__device__ __forceinline__ float sigm(float x) { return 1.0f / (1.0f + __expf(-x)); }
__device__ __forceinline__ float ftanh(float x) {
  return 1.0f - 2.0f / (1.0f + __expf(2.0f * x));
}
__device__ __forceinline__ f32x4 ld4(const float* p) { return *(const f32x4*)p; }
__device__ __forceinline__ void ntst4(float* p, f32x4 v) {
  __builtin_nontemporal_store(v, (f32x4*)p);
}

// ---------------------------------------------------------------------------
// Weight pre-pack: f32 [CO][CI][3][3] -> bf16 [K/8][CO][8], K = tap*CI + ci.
// ---------------------------------------------------------------------------
__global__ void pack_w(const float* __restrict__ w1, const float* __restrict__ w2,
                       const float* __restrict__ w3, short* __restrict__ out) {
  int e = blockIdx.x * 256 + threadIdx.x;
  if (e < 46080) {
    int kb8 = e / 320, n = e % 320;
    short8 v;
#pragma unroll
    for (int j = 0; j < 8; ++j) {
      int k = kb8 * 8 + j;
      int tap = k >> 7, ci = k & 127;
      v[j] = f2bf(w1[(n * 128 + ci) * 9 + tap]);
    }
    *(short8*)&out[e * 8] = v;
    return;
  }
  e -= 46080;
  if (e < 13824) {
    int kb8 = e / 192, n = e % 192;
    short8 v;
#pragma unroll
    for (int j = 0; j < 8; ++j) {
      int k = kb8 * 8 + j;
      int tap = k >> 6, ci = k & 63;
      v[j] = f2bf(w2[(n * 64 + ci) * 9 + tap]);
    }
    *(short8*)&out[(46080 + e) * 8] = v;
    return;
  }
  e -= 13824;
  {
    int kb8 = e / 64, n = e % 64;
    short8 v;
#pragma unroll
    for (int j = 0; j < 8; ++j) {
      int k = kb8 * 8 + j;
      int tap = k >> 6, ci = k & 63;
      v[j] = f2bf(w3[(n * 64 + ci) * 9 + tap]);
    }
    *(short8*)&out[(46080 + 13824 + e) * 8] = v;
  }
}

// ===========================================================================
// R15 main path: R14 (25.5 KB LDS, launch_bounds(512,4), VGPR 56) with ONE
// change — role INTERLEAVE (role = blockIdx&1) so attn blocks (global-latency
// -bound K-stream) and gate blocks (MFMA/LDS-bound conv1) co-reside on each
// CU in dispatch order, instead of running as two sequential phases.
//   mid4_k even blocks=attn: conv2 -> strided k7/v7 -> q via combf -> K-stream
//     -> softmax -> ws_wt.  odd blocks=gate: conv1 -> strided c_cur reload
//     -> ct/oa strided stores.
//   tail_k: verbatim R8 (softmax weights in, V-stream + PV + conv3 + LN).
// ===========================================================================
__launch_bounds__(512, 4)
__global__ void mid4_k(const float* __restrict__ input, const float* __restrict__ h_cur,
                       const float* __restrict__ c_cur, const float* __restrict__ ck,
                       const int* __restrict__ amask,
                       const float* __restrict__ conv_b, const float* __restrict__ proj_b,
                       const float* __restrict__ pos_w, const float* __restrict__ pos_b,
                       const short* __restrict__ pk1, const short* __restrict__ pk2,
                       float* __restrict__ o_k, float* __restrict__ o_v,
                       float* __restrict__ ws_wt, float* __restrict__ ws_ct,
                       unsigned* __restrict__ ws_oa) {
  __shared__ short comb[12800];  // 25.6 KB total LDS (plus sc_lds)
  __shared__ float sc_lds[8];
  float* combf = (float*)comb;   // 6400 floats capacity; q uses 4160

  const int tid = threadIdx.x;
  const int wave = tid >> 6, lane = tid & 63;
  const int col = lane & 15, g4 = lane >> 4;
  const int wc = wave >> 1, wm = wave & 1;
  const int ch = wc * 16 + col;
  const int role = blockIdx.x & 1;   // R15: interleaved roles
  const int b = blockIdx.x >> 1;

  if (role == 0) {
    // ---------------- ATTENTION (conv2 + K-stream + softmax) ----------------
    if (tid < 8) sc_lds[tid] = 0.f;

    // stage input -> 64ch rotated bf16 tile
#pragma unroll
    for (int i = 0; i < 2; ++i) {
      int idx = (tid + 512 * i) * 4;
      int c = idx >> 6, p0 = idx & 63;
      f32x4 vi = ld4(&input[b * 4096 + idx]);
#pragma unroll
      for (int j = 0; j < 4; ++j) {
        int p = p0 + j;
        int pp = ((p >> 3) + 1) * 10 + (p & 7) + 1;
        comb[pp * 64 + ((c + pp * 8) & 63)] = f2bf(vi[j]);
      }
    }
    for (int i = tid; i < 2304; i += 512) {  // pad ring
      int pr = i >> 6, c = i & 63;
      int pp = (pr < 10) ? pr
               : (pr < 20) ? (80 + pr)
               : (pr < 28) ? ((pr - 19) * 10)
                           : ((pr - 27) * 10 + 9);
      comb[pp * 64 + c] = 0;
    }
    __syncthreads();

    // conv2: M=64 N=192 K=576
    f32x4 acc2[2][3];
#pragma unroll
    for (int m = 0; m < 2; ++m)
#pragma unroll
      for (int g = 0; g < 3; ++g) acc2[m][g] = (f32x4){0.f, 0.f, 0.f, 0.f};
    short8 bb2[3];
#pragma unroll
    for (int g = 0; g < 3; ++g)
      bb2[g] = *(const short8*)&pk2[((g4)*192 + g * 64 + ch) * 8];
    for (int s = 0; s < 18; ++s) {
      short8 bbn[3];
      if (s < 17) {
        int kb8 = (s + 1) * 4 + g4;
#pragma unroll
        for (int g = 0; g < 3; ++g)
          bbn[g] = *(const short8*)&pk2[(kb8 * 192 + g * 64 + ch) * 8];
      }
      int tap = s >> 1, cib = s & 1;
      int kh = tap / 3, kw = tap % 3;
      short8 a[2];
#pragma unroll
      for (int m = 0; m < 2; ++m) {
        int p = (wm * 2 + m) * 16 + col;
        int pp = ((p >> 3) + kh) * 10 + (p & 7) + kw;
        int slot = (cib * 32 + g4 * 8 + pp * 8) & 63;
        a[m] = *(const short8*)&comb[pp * 64 + slot];
      }
#pragma unroll
      for (int m = 0; m < 2; ++m)
#pragma unroll
        for (int g = 0; g < 3; ++g) acc2[m][g] = mfma16(a[m], bb2[g], acc2[m][g]);
      if (s < 17) {
#pragma unroll
        for (int g = 0; g < 3; ++g) bb2[g] = bbn[g];
      }
    }

    // epilogue: strided k7/v7 stores (R10-verified), q in regs, part7
    float qreg[8], part7 = 0.f;
    {
      float pb0 = proj_b[ch], pb1 = proj_b[64 + ch], pb2 = proj_b[128 + ch];
      const float rsq = 0.044194173824159216f;  // 1/sqrt(512)
      const size_t base7 = (size_t)(b * 8 + 7) * 4096;
#pragma unroll
      for (int m2 = 0; m2 < 2; ++m2) {
        int p0 = wm * 32 + m2 * 16 + g4 * 4;
        f32x4 pw7 = ld4(&pos_w[7 * 4096 + ch * 64 + p0]);
        f32x4 kq, vq;
#pragma unroll
        for (int r = 0; r < 4; ++r) {
          float kf = acc2[m2][0][r] + pb0 + pw7[r];
          float qf = (acc2[m2][1][r] + pb1) * rsq;
          float vf = acc2[m2][2][r] + pb2;
          kq[r] = kf;
          vq[r] = vf;
          qreg[m2 * 4 + r] = qf;
          part7 = fmaf(qf, kf, part7);
        }
        *(f32x4*)&o_k[base7 + ch * 64 + p0] = kq;
        *(f32x4*)&o_v[base7 + ch * 64 + p0] = vq;  // re-read by tail_k
      }
    }
    atomicAdd(&sc_lds[ch >> 3], part7);

    // hoist per-slot uniforms
    int msks[7];
    float pbv[7];
    const int hd = wave;
#pragma unroll
    for (int m = 0; m < 7; ++m) {
      msks[m] = amask[(b * 8 + hd) * 8 + m];
      pbv[m] = pos_b[m * 8 + hd];
    }

    __syncthreads();  // all conv2 comb reads done; atomics complete

    // q -> combf (comb reused; 4160 floats < 6400 capacity)
#pragma unroll
    for (int m2 = 0; m2 < 2; ++m2) {
      int p0 = wm * 32 + m2 * 16 + g4 * 4;
#pragma unroll
      for (int r = 0; r < 4; ++r) combf[ch * 65 + p0 + r] = qreg[m2 * 4 + r];
    }
    __syncthreads();

    const int d0 = lane * 4, d1 = (lane + 64) * 4;
    const int cs0 = d0 >> 6, po0 = d0 & 63, cs1 = d1 >> 6, po1 = d1 & 63;
    f32x4 q0, q1;
#pragma unroll
    for (int j = 0; j < 4; ++j) {
      q0[j] = combf[(hd * 8 + cs0) * 65 + po0 + j];
      q1[j] = combf[(hd * 8 + cs1) * 65 + po1 + j];
    }
    float sc7 = sc_lds[hd] + pos_b[7 * 8 + hd] + 5.0f;  // attn_mask_b

    // K-stream (R8's sequential form)
    float scv[8];
    scv[7] = sc7;
#pragma unroll
    for (int m = 0; m < 7; ++m) {
      const float* kp = ck + ((size_t)((b * 8 + m + 1) * 8 + hd)) * 512;
      const float* pw = pos_w + m * 4096 + hd * 512;
      f32x4 k0 = ld4(kp + d0) + ld4(pw + d0);
      f32x4 k1 = ld4(kp + d1) + ld4(pw + d1);
      float* dst = o_k + ((size_t)((b * 8 + m) * 8 + hd)) * 512;
      ntst4(dst + d0, k0);
      ntst4(dst + d1, k1);
      float part = 0.f;
#pragma unroll
      for (int j = 0; j < 4; ++j) {
        part = fmaf(q0[j], k0[j], part);
        part = fmaf(q1[j], k1[j], part);
      }
#pragma unroll
      for (int off = 32; off >= 1; off >>= 1) part += __shfl_xor(part, off);
      scv[m] = part + pbv[m] + (msks[m] ? -__builtin_inff() : 0.0f);
    }

    // softmax (redundant per lane), lane 0 writes
    float mx = scv[0];
#pragma unroll
    for (int m = 1; m < 8; ++m) mx = fmaxf(mx, scv[m]);
    float w[8], s = 0.f;
#pragma unroll
    for (int m = 0; m < 8; ++m) {
      w[m] = __expf(scv[m] - mx);
      s += w[m];
    }
    float inv = 1.0f / s;
    if (lane == 0) {
#pragma unroll
      for (int m = 0; m < 8; ++m)
        ws_wt[(size_t)b * 64 + hd * 8 + m] = w[m] * inv;
    }
  } else {
    // ---------------- GATE BLOCK (conv1, no LDS staging of c) ----------------
#pragma unroll
    for (int i = 0; i < 2; ++i) {
      int idx = (tid + 512 * i) * 4;
      int c = idx >> 6, p0 = idx & 63;
      f32x4 vi = ld4(&input[b * 4096 + idx]);
      f32x4 vh = ld4(&h_cur[b * 4096 + idx]);
#pragma unroll
      for (int j = 0; j < 4; ++j) {
        int p = p0 + j;
        int pp = ((p >> 3) + 1) * 10 + (p & 7) + 1;
        comb[pp * 128 + ((c + pp * 8) & 127)] = f2bf(vi[j]);
        comb[pp * 128 + ((c + 64 + pp * 8) & 127)] = f2bf(vh[j]);
      }
    }
    for (int i = tid; i < 4608; i += 512) {  // pad ring
      int pr = i >> 7, c = i & 127;
      int pp = (pr < 10) ? pr
               : (pr < 20) ? (80 + pr)
               : (pr < 28) ? ((pr - 19) * 10)
                           : ((pr - 27) * 10 + 9);
      comb[pp * 128 + c] = 0;
    }
    __syncthreads();

    // conv1: M=64 N=320 K=1152
    f32x4 acc1[2][5];
#pragma unroll
    for (int m = 0; m < 2; ++m)
#pragma unroll
      for (int g = 0; g < 5; ++g) acc1[m][g] = (f32x4){0.f, 0.f, 0.f, 0.f};
    short8 bb1[5];
#pragma unroll
    for (int g = 0; g < 5; ++g)
      bb1[g] = *(const short8*)&pk1[((g4)*320 + g * 64 + ch) * 8];
    for (int s = 0; s < 36; ++s) {
      short8 bbn[5];
      if (s < 35) {
        int kb8 = (s + 1) * 4 + g4;
#pragma unroll
        for (int g = 0; g < 5; ++g)
          bbn[g] = *(const short8*)&pk1[(kb8 * 320 + g * 64 + ch) * 8];
      }
      int tap = s >> 2, cib = s & 3;
      int kh = tap / 3, kw = tap % 3;
      short8 a[2];
#pragma unroll
      for (int m = 0; m < 2; ++m) {
        int p = (wm * 2 + m) * 16 + col;
        int pp = ((p >> 3) + kh) * 10 + (p & 7) + kw;
        int slot = (cib * 32 + g4 * 8 + pp * 8) & 127;
        a[m] = *(const short8*)&comb[pp * 128 + slot];
      }
#pragma unroll
      for (int m = 0; m < 2; ++m)
#pragma unroll
        for (int g = 0; g < 5; ++g) acc1[m][g] = mfma16(a[m], bb1[g], acc1[m][g]);
      if (s < 35) {
#pragma unroll
        for (int g = 0; g < 5; ++g) bb1[g] = bbn[g];
      }
    }

    // epilogue: c_cur strided reload; ct/oa strided stores (layout [ch*64+p])
    {
      float bi0 = conv_b[ch], bi1 = conv_b[64 + ch], bi2 = conv_b[128 + ch];
      float bi3 = conv_b[192 + ch], bi4 = conv_b[256 + ch];
#pragma unroll
      for (int m2 = 0; m2 < 2; ++m2) {
        int p0 = wm * 32 + m2 * 16 + g4 * 4;
        f32x4 cr = ld4(&c_cur[(size_t)b * 4096 + ch * 64 + p0]);
        f32x4 cq;
        u32x4 oq;
#pragma unroll
        for (int r = 0; r < 4; ++r) {
          float iv = sigm(acc1[m2][0][r] + bi0);
          float fv = sigm(acc1[m2][1][r] + bi1);
          float ov = sigm(acc1[m2][2][r] + bi2);
          float gv = ftanh(acc1[m2][3][r] + bi3);
          float av = sigm(acc1[m2][4][r] + bi4);
          cq[r] = fv * cr[r] + iv * gv;
          oq[r] = ((unsigned)(unsigned short)f2bf(av) << 16) |
                  (unsigned)(unsigned short)f2bf(ov);
        }
        *(f32x4*)&ws_ct[(size_t)b * 4096 + ch * 64 + p0] = cq;
        *(u32x4*)&ws_oa[(size_t)b * 4096 + ch * 64 + p0] = oq;
      }
    }
  }
}

// ---------------------------------------------------------------------------
// tail_k: softmax weights in; V-stream + PV + conv3 + residual + LN + epilogue.
// (verbatim R8)
// ---------------------------------------------------------------------------
__launch_bounds__(512, 4)
__global__ void tail_k(const float* __restrict__ input, const float* __restrict__ cv,
                       const float* __restrict__ ws_wt,
                       const float* __restrict__ ws_ct,
                       const unsigned* __restrict__ ws_oa,
                       const float* __restrict__ out_b,
                       const float* __restrict__ ln_w, const float* __restrict__ ln_b,
                       const short* __restrict__ pk3,
                       float* __restrict__ o_h, float* __restrict__ o_c,
                       float* __restrict__ o_v) {
  __shared__ short comb[8320];
  __shared__ float Xb[4160];
  __shared__ float wt_s[64];
  __shared__ float red[16];
  float* combf = (float*)comb;
  unsigned* Xbu = (unsigned*)Xb;

  const int b = blockIdx.x;
  const int tid = threadIdx.x;
  const int wave = tid >> 6, lane = tid & 63;
  const int col = lane & 15, g4 = lane >> 4;
  const int wc = wave >> 1, wm = wave & 1;
  const int ch = wc * 16 + col;
  const int hd = wave;
  const int d0 = lane * 4, d1 = (lane + 64) * 4;

  f32x4 ctr[2];
  u32x4 oar[2];
#pragma unroll
  for (int i = 0; i < 2; ++i) {
    int idx = (tid + 512 * i) * 4;
    ctr[i] = ld4(&ws_ct[(size_t)b * 4096 + idx]);
    oar[i] = *(const u32x4*)&ws_oa[(size_t)b * 4096 + idx];
  }
  if (tid < 64) wt_s[tid] = ws_wt[(size_t)b * 64 + tid];

#pragma unroll
  for (int i = 0; i < 2; ++i) {
    int idx = (tid + 512 * i) * 4;
    int c = idx >> 6, p0 = idx & 63;
    f32x4 vi = ld4(&input[b * 4096 + idx]);
#pragma unroll
    for (int j = 0; j < 4; ++j) Xb[c * 65 + p0 + j] = vi[j];
  }
  for (int i = tid; i < 2304; i += 512) {  // pad ring
    int pr = i >> 6, c = i & 63;
    int pp = (pr < 10) ? pr
             : (pr < 20) ? (80 + pr)
             : (pr < 28) ? ((pr - 19) * 10)
                         : ((pr - 27) * 10 + 9);
    comb[pp * 64 + c] = 0;
  }
  __syncthreads();  // wt_s ready

  float wv[8];
#pragma unroll
  for (int m = 0; m < 8; ++m) wv[m] = wt_s[hd * 8 + m];

  f32x4 a0 = (f32x4){0.f, 0.f, 0.f, 0.f};
  f32x4 a1 = (f32x4){0.f, 0.f, 0.f, 0.f};
#pragma unroll
  for (int m = 0; m < 7; ++m) {
    const float* vp = cv + ((size_t)((b * 8 + m + 1) * 8 + hd)) * 512;
    f32x4 v0 = ld4(vp + d0);
    f32x4 v1 = ld4(vp + d1);
    float* dst = o_v + ((size_t)((b * 8 + m) * 8 + hd)) * 512;
    ntst4(dst + d0, v0);
    ntst4(dst + d1, v1);
    a0 += v0 * wv[m];
    a1 += v1 * wv[m];
  }
  {
    const float* vp = o_v + ((size_t)((b * 8 + 7) * 8 + hd)) * 512;
    a0 += ld4(vp + d0) * wv[7];
    a1 += ld4(vp + d1) * wv[7];
  }
#pragma unroll
  for (int j = 0; j < 4; ++j) {
    int dA = d0 + j, dB = d1 + j;
    int cA = hd * 8 + (dA >> 6), pA = dA & 63;
    int cB = hd * 8 + (dB >> 6), pB = dB & 63;
    int ppA = ((pA >> 3) + 1) * 10 + (pA & 7) + 1;
    int ppB = ((pB >> 3) + 1) * 10 + (pB & 7) + 1;
    comb[ppA * 64 + ((cA + ppA * 8) & 63)] = f2bf(a0[j]);
    comb[ppB * 64 + ((cB + ppB * 8) & 63)] = f2bf(a1[j]);
  }
  __syncthreads();

  // conv3: M=64 N=64 K=576
  f32x4 acc3[2];
  acc3[0] = (f32x4){0.f, 0.f, 0.f, 0.f};
  acc3[1] = (f32x4){0.f, 0.f, 0.f, 0.f};
  short8 bb3 = *(const short8*)&pk3[((g4)*64 + ch) * 8];
  for (int s = 0; s < 18; ++s) {
    short8 bbn;
    if (s < 17) {
      int kb8 = (s + 1) * 4 + g4;
      bbn = *(const short8*)&pk3[(kb8 * 64 + ch) * 8];
    }
    int tap = s >> 1, cib = s & 1;
    int kh = tap / 3, kw = tap % 3;
    short8 a[2];
#pragma unroll
    for (int m = 0; m < 2; ++m) {
      int p = (wm * 2 + m) * 16 + col;
      int pp = ((p >> 3) + kh) * 10 + (p & 7) + kw;
      int slot = (cib * 32 + g4 * 8 + pp * 8) & 63;
      a[m] = *(const short8*)&comb[pp * 64 + slot];
    }
#pragma unroll
    for (int m = 0; m < 2; ++m) acc3[m] = mfma16(a[m], bb3, acc3[m]);
    if (s < 17) bb3 = bbn;
  }

  float ov_[8], s1 = 0.f, s2 = 0.f;
  {
    float ob = out_b[ch];
#pragma unroll
    for (int m = 0; m < 2; ++m)
#pragma unroll
      for (int r = 0; r < 4; ++r) {
        int p = (wm * 2 + m) * 16 + g4 * 4 + r;
        float v = acc3[m][r] + ob + Xb[ch * 65 + p];
        ov_[m * 4 + r] = v;
        s1 += v;
        s2 += v * v;
      }
  }
#pragma unroll
  for (int off = 32; off >= 1; off >>= 1) {
    s1 += __shfl_xor(s1, off);
    s2 += __shfl_xor(s2, off);
  }
  if (lane == 0) { red[wave] = s1; red[8 + wave] = s2; }
  __syncthreads();
  float ts1 = 0.f, ts2 = 0.f;
#pragma unroll
  for (int w = 0; w < 8; ++w) { ts1 += red[w]; ts2 += red[8 + w]; }
  float mu = ts1 * (1.0f / 4096.0f);
  float var = ts2 * (1.0f / 4096.0f) - mu * mu;
  float rstd = rsqrtf(var + 1e-5f);

#pragma unroll
  for (int i = 0; i < 2; ++i) {
    int idx = (tid + 512 * i) * 4;
    int c = idx >> 6, p0 = idx & 63;
#pragma unroll
    for (int j = 0; j < 4; ++j) {
      combf[c * 65 + p0 + j] = ctr[i][j];
      Xbu[c * 65 + p0 + j] = oar[i][j];
    }
  }
  __syncthreads();

#pragma unroll
  for (int m = 0; m < 2; ++m)
#pragma unroll
    for (int r = 0; r < 4; ++r) {
      int p = (wm * 2 + m) * 16 + g4 * 4 + r;
      float ct = combf[ch * 65 + p];
      unsigned u = Xbu[ch * 65 + p];
      float og = __builtin_bit_cast(float, u << 16);
      float ag = __builtin_bit_cast(float, u & 0xffff0000u);
      float oln = (ov_[m * 4 + r] - mu) * rstd * ln_w[ch * 64 + p] + ln_b[ch * 64 + p];
      float cn = ct + ag * ftanh(oln);
      float hv = og * ftanh(cn);
      combf[ch * 65 + p] = hv;
      Xb[ch * 65 + p] = cn;
    }
  __syncthreads();
#pragma unroll
  for (int i = 0; i < 2; ++i) {
    int idx = (tid + 512 * i) * 4;
    int c = idx >> 6, p0 = idx & 63;
    f32x4 hq, cq;
#pragma unroll
    for (int j = 0; j < 4; ++j) {
      hq[j] = combf[c * 65 + p0 + j];
      cq[j] = Xb[c * 65 + p0 + j];
    }
    *(f32x4*)&o_h[b * 4096 + idx] = hq;
    *(f32x4*)&o_c[b * 4096 + idx] = cq;
  }
}

// ===========================================================================
// Fallback path (R3, proven): used only if ws_size < 32 MB.
// ===========================================================================
__launch_bounds__(512, 4)
__global__ void kqv_k(const float* __restrict__ input,
                      const float* __restrict__ proj_b,
                      const float* __restrict__ pos_w,
                      const short* __restrict__ pk2,
                      float* __restrict__ q_out, float* __restrict__ o_k,
                      float* __restrict__ o_v) {
  __shared__ short comb[6400];
  __shared__ float Xk[4160], Xq[4160], Xv[4160];
  const int b = blockIdx.x;
  const int tid = threadIdx.x;
  const int wave = tid >> 6, lane = tid & 63;
  const int col = lane & 15, g4 = lane >> 4;
  const int wc = wave >> 1, wm = wave & 1;
  const int ch = wc * 16 + col;
#pragma unroll
  for (int i = 0; i < 2; ++i) {
    int idx = (tid + 512 * i) * 4;
    int c = idx >> 6, p0 = idx & 63;
    f32x4 vi = ld4(&input[b * 4096 + idx]);
#pragma unroll
    for (int j = 0; j < 4; ++j) {
      int p = p0 + j;
      int pp = ((p >> 3) + 1) * 10 + (p & 7) + 1;
      comb[pp * 64 + ((c + pp * 8) & 63)] = f2bf(vi[j]);
    }
  }
  for (int i = tid; i < 2304; i += 512) {
    int pr = i >> 6, c = i & 63;
    int pp = (pr < 10) ? pr
             : (pr < 20) ? (80 + pr)
             : (pr < 28) ? ((pr - 19) * 10)
                         : ((pr - 27) * 10 + 9);
    comb[pp * 64 + c] = 0;
  }
  __syncthreads();
  f32x4 acc2[2][3];
#pragma unroll
  for (int m = 0; m < 2; ++m)
#pragma unroll
    for (int g = 0; g < 3; ++g) acc2[m][g] = (f32x4){0.f, 0.f, 0.f, 0.f};
  short8 bb2[3];
#pragma unroll
  for (int g = 0; g < 3; ++g)
    bb2[g] = *(const short8*)&pk2[((g4)*192 + g * 64 + ch) * 8];
  for (int s = 0; s < 18; ++s) {
    short8 bbn[3];
    if (s < 17) {
      int kb8 = (s + 1) * 4 + g4;
#pragma unroll
      for (int g = 0; g < 3; ++g)
        bbn[g] = *(const short8*)&pk2[(kb8 * 192 + g * 64 + ch) * 8];
    }
    int tap = s >> 1, cib = s & 1;
    int kh = tap / 3, kw = tap % 3;
    short8 a[2];
#pragma unroll
    for (int m = 0; m < 2; ++m) {
      int p = (wm * 2 + m) * 16 + col;
      int pp = ((p >> 3) + kh) * 10 + (p & 7) + kw;
      int slot = (cib * 32 + g4 * 8 + pp * 8) & 63;
      a[m] = *(const short8*)&comb[pp * 64 + slot];
    }
#pragma unroll
    for (int m = 0; m < 2; ++m)
#pragma unroll
      for (int g = 0; g < 3; ++g) acc2[m][g] = mfma16(a[m], bb2[g], acc2[m][g]);
    if (s < 17) {
#pragma unroll
      for (int g = 0; g < 3; ++g) bb2[g] = bbn[g];
    }
  }
  {
    float pb0 = proj_b[ch], pb1 = proj_b[64 + ch], pb2 = proj_b[128 + ch];
    const float rsq = 0.044194173824159216f;
#pragma unroll
    for (int m = 0; m < 2; ++m)
#pragma unroll
      for (int r = 0; r < 4; ++r) {
        int p = (wm * 2 + m) * 16 + g4 * 4 + r;
        Xk[ch * 65 + p] = acc2[m][0][r] + pb0 + pos_w[7 * 4096 + ch * 64 + p];
        Xq[ch * 65 + p] = (acc2[m][1][r] + pb1) * rsq;
        Xv[ch * 65 + p] = acc2[m][2][r] + pb2;
      }
  }
  __syncthreads();
  const size_t base7 = (size_t)(b * 64 + 56) * 512;
#pragma unroll
  for (int i = 0; i < 2; ++i) {
    int idx = (tid + 512 * i) * 4;
    int c = idx >> 6, p0 = idx & 63;
    f32x4 kq, qq, vq;
#pragma unroll
    for (int j = 0; j < 4; ++j) {
      kq[j] = Xk[c * 65 + p0 + j];
      qq[j] = Xq[c * 65 + p0 + j];
      vq[j] = Xv[c * 65 + p0 + j];
    }
    *(f32x4*)&o_k[base7 + idx] = kq;
    *(f32x4*)&q_out[(size_t)b * 4096 + idx] = qq;
    *(f32x4*)&o_v[base7 + idx] = vq;
  }
}

__launch_bounds__(64, 4)
__global__ void attn_k(const float* __restrict__ ck, const float* __restrict__ cv,
                       const int* __restrict__ amask,
                       const float* __restrict__ pos_w,
                       const float* __restrict__ pos_b,
                       const float* __restrict__ q_in,
                       float* __restrict__ o_k, float* __restrict__ o_v,
                       float* __restrict__ attn_out) {
  const int b = blockIdx.x >> 3;
  const int hd = blockIdx.x & 7;
  const int lane = threadIdx.x;
  const int d0 = lane * 4, d1 = (lane + 64) * 4;
  const float* qp = q_in + (size_t)b * 4096 + hd * 512;
  f32x4 q0 = ld4(qp + d0);
  f32x4 q1 = ld4(qp + d1);
  float sc[8];
#pragma unroll
  for (int m = 0; m < 7; ++m) {
    const float* kp = ck + ((size_t)((b * 8 + m + 1) * 8 + hd)) * 512;
    const float* pw = pos_w + m * 4096 + hd * 512;
    f32x4 k0 = ld4(kp + d0) + ld4(pw + d0);
    f32x4 k1 = ld4(kp + d1) + ld4(pw + d1);
    float* dst = o_k + ((size_t)((b * 8 + m) * 8 + hd)) * 512;
    ntst4(dst + d0, k0);
    ntst4(dst + d1, k1);
    float part = 0.f;
#pragma unroll
    for (int j = 0; j < 4; ++j) {
      part = fmaf(q0[j], k0[j], part);
      part = fmaf(q1[j], k1[j], part);
    }
#pragma unroll
    for (int off = 32; off >= 1; off >>= 1) part += __shfl_xor(part, off);
    float msk = amask[(b * 8 + hd) * 8 + m] ? -__builtin_inff() : 0.0f;
    sc[m] = part + pos_b[m * 8 + hd] + msk;
  }
  {
    const float* kp = o_k + ((size_t)((b * 8 + 7) * 8 + hd)) * 512;
    f32x4 k0 = ld4(kp + d0);
    f32x4 k1 = ld4(kp + d1);
    float part = 0.f;
#pragma unroll
    for (int j = 0; j < 4; ++j) {
      part = fmaf(q0[j], k0[j], part);
      part = fmaf(q1[j], k1[j], part);
    }
#pragma unroll
    for (int off = 32; off >= 1; off >>= 1) part += __shfl_xor(part, off);
    sc[7] = part + pos_b[7 * 8 + hd] + 5.0f;
  }
  float mx = sc[0];
#pragma unroll
  for (int m = 1; m < 8; ++m) mx = fmaxf(mx, sc[m]);
  float w[8], s = 0.f;
#pragma unroll
  for (int m = 0; m < 8; ++m) {
    w[m] = __expf(sc[m] - mx);
    s += w[m];
  }
  float inv = 1.0f / s;
#pragma unroll
  for (int m = 0; m < 8; ++m) w[m] *= inv;
  f32x4 a0 = (f32x4){0.f, 0.f, 0.f, 0.f};
  f32x4 a1 = (f32x4){0.f, 0.f, 0.f, 0.f};
#pragma unroll
  for (int m = 0; m < 7; ++m) {
    const float* vp = cv + ((size_t)((b * 8 + m + 1) * 8 + hd)) * 512;
    f32x4 v0 = ld4(vp + d0);
    f32x4 v1 = ld4(vp + d1);
    float* dst = o_v + ((size_t)((b * 8 + m) * 8 + hd)) * 512;
    ntst4(dst + d0, v0);
    ntst4(dst + d1, v1);
    a0 += v0 * w[m];
    a1 += v1 * w[m];
  }
  {
    const float* vp = o_v + ((size_t)((b * 8 + 7) * 8 + hd)) * 512;
    a0 += ld4(vp + d0) * w[7];
    a1 += ld4(vp + d1) * w[7];
  }
  float* ap = attn_out + (size_t)b * 4096 + hd * 512;
  *(f32x4*)&ap[d0] = a0;
  *(f32x4*)&ap[d1] = a1;
}

__launch_bounds__(512, 4)
__global__ void cell2_k(
    const float* __restrict__ input, const float* __restrict__ h_cur,
    const float* __restrict__ c_cur, const float* __restrict__ attn_in,
    const float* __restrict__ conv_b, const float* __restrict__ out_b,
    const float* __restrict__ ln_w, const float* __restrict__ ln_b,
    const short* __restrict__ pk1, const short* __restrict__ pk3,
    float* __restrict__ o_h, float* __restrict__ o_c) {
  __shared__ short comb[12800];
  __shared__ float Xb[4160];
  __shared__ float Qb[4160];
  __shared__ float Vb[4160];
  __shared__ float red[16];
  const int b = blockIdx.x;
  const int tid = threadIdx.x;
  const int wave = tid >> 6, lane = tid & 63;
  const int col = lane & 15, g4 = lane >> 4;
  const int wc = wave >> 1, wm = wave & 1;
  const int ch = wc * 16 + col;
#pragma unroll
  for (int i = 0; i < 2; ++i) {
    int idx = (tid + 512 * i) * 4;
    int c = idx >> 6, p0 = idx & 63;
    f32x4 vi = ld4(&input[b * 4096 + idx]);
    f32x4 vh = ld4(&h_cur[b * 4096 + idx]);
    f32x4 vc = ld4(&c_cur[b * 4096 + idx]);
#pragma unroll
    for (int j = 0; j < 4; ++j) {
      int p = p0 + j;
      int pp = ((p >> 3) + 1) * 10 + (p & 7) + 1;
      comb[pp * 128 + ((c + pp * 8) & 127)] = f2bf(vi[j]);
      comb[pp * 128 + ((c + 64 + pp * 8) & 127)] = f2bf(vh[j]);
      Xb[c * 65 + p] = vc[j];
    }
  }
  for (int i = tid; i < 4608; i += 512) {
    int pr = i >> 7, c = i & 127;
    int pp = (pr < 10) ? pr
             : (pr < 20) ? (80 + pr)
             : (pr < 28) ? ((pr - 19) * 10)
                         : ((pr - 27) * 10 + 9);
    comb[pp * 128 + c] = 0;
  }
  __syncthreads();
  f32x4 acc1[2][5];
#pragma unroll
  for (int m = 0; m < 2; ++m)
#pragma unroll
    for (int g = 0; g < 5; ++g) acc1[m][g] = (f32x4){0.f, 0.f, 0.f, 0.f};
  short8 bb1[5];
#pragma unroll
  for (int g = 0; g < 5; ++g)
    bb1[g] = *(const short8*)&pk1[((g4)*320 + g * 64 + ch) * 8];
  for (int s = 0; s < 36; ++s) {
    short8 bbn[5];
    if (s < 35) {
      int kb8 = (s + 1) * 4 + g4;
#pragma unroll
      for (int g = 0; g < 5; ++g)
        bbn[g] = *(const short8*)&pk1[(kb8 * 320 + g * 64 + ch) * 8];
    }
    int tap = s >> 2, cib = s & 3;
    int kh = tap / 3, kw = tap % 3;
    short8 a[2];
#pragma unroll
    for (int m = 0; m < 2; ++m) {
      int p = (wm * 2 + m) * 16 + col;
      int pp = ((p >> 3) + kh) * 10 + (p & 7) + kw;
      int slot = (cib * 32 + g4 * 8 + pp * 8) & 127;
      a[m] = *(const short8*)&comb[pp * 128 + slot];
    }
#pragma unroll
    for (int m = 0; m < 2; ++m)
#pragma unroll
      for (int g = 0; g < 5; ++g) acc1[m][g] = mfma16(a[m], bb1[g], acc1[m][g]);
    if (s < 35) {
#pragma unroll
      for (int g = 0; g < 5; ++g) bb1[g] = bbn[g];
    }
  }
  float ct_r[8], o_r[8], a_r[8];
  {
    float bi0 = conv_b[ch], bi1 = conv_b[64 + ch], bi2 = conv_b[128 + ch];
    float bi3 = conv_b[192 + ch], bi4 = conv_b[256 + ch];
#pragma unroll
    for (int m = 0; m < 2; ++m)
#pragma unroll
      for (int r = 0; r < 4; ++r) {
        int p = (wm * 2 + m) * 16 + g4 * 4 + r;
        float iv = sigm(acc1[m][0][r] + bi0);
        float fv = sigm(acc1[m][1][r] + bi1);
        float ov = sigm(acc1[m][2][r] + bi2);
        float gv = ftanh(acc1[m][3][r] + bi3);
        float av = sigm(acc1[m][4][r] + bi4);
        ct_r[m * 4 + r] = fv * Xb[ch * 65 + p] + iv * gv;
        o_r[m * 4 + r] = ov;
        a_r[m * 4 + r] = av;
      }
  }
  __syncthreads();
  {
    f32x4 av[2], iv[2];
#pragma unroll
    for (int i = 0; i < 2; ++i) {
      int idx = (tid + 512 * i) * 4;
      av[i] = ld4(&attn_in[b * 4096 + idx]);
      iv[i] = ld4(&input[b * 4096 + idx]);
    }
#pragma unroll
    for (int i = 0; i < 2; ++i) {
      int idx = (tid + 512 * i) * 4;
      int c = idx >> 6, p0 = idx & 63;
#pragma unroll
      for (int j = 0; j < 4; ++j) {
        int p = p0 + j;
        int pp = ((p >> 3) + 1) * 10 + (p & 7) + 1;
        comb[pp * 128 + ((c + pp * 8) & 127)] = f2bf(av[i][j]);
        Xb[c * 65 + p] = iv[i][j];
      }
    }
  }
  __syncthreads();
  f32x4 acc3[2];
  acc3[0] = (f32x4){0.f, 0.f, 0.f, 0.f};
  acc3[1] = (f32x4){0.f, 0.f, 0.f, 0.f};
  short8 bb3 = *(const short8*)&pk3[((g4)*64 + ch) * 8];
  for (int s = 0; s < 18; ++s) {
    short8 bbn;
    if (s < 17) {
      int kb8 = (s + 1) * 4 + g4;
      bbn = *(const short8*)&pk3[(kb8 * 64 + ch) * 8];
    }
    int tap = s >> 1, cib = s & 1;
    int kh = tap / 3, kw = tap % 3;
    short8 a[2];
#pragma unroll
    for (int m = 0; m < 2; ++m) {
      int p = (wm * 2 + m) * 16 + col;
      int pp = ((p >> 3) + kh) * 10 + (p & 7) + kw;
      int slot = (cib * 32 + g4 * 8 + pp * 8) & 127;
      a[m] = *(const short8*)&comb[pp * 128 + slot];
    }
#pragma unroll
    for (int m = 0; m < 2; ++m) acc3[m] = mfma16(a[m], bb3, acc3[m]);
    if (s < 17) bb3 = bbn;
  }
  float ov_[8], s1 = 0.f, s2 = 0.f;
  {
    float ob = out_b[ch];
#pragma unroll
    for (int m = 0; m < 2; ++m)
#pragma unroll
      for (int r = 0; r < 4; ++r) {
        int p = (wm * 2 + m) * 16 + g4 * 4 + r;
        float v = acc3[m][r] + ob + Xb[ch * 65 + p];
        ov_[m * 4 + r] = v;
        s1 += v;
        s2 += v * v;
      }
  }
#pragma unroll
  for (int off = 32; off >= 1; off >>= 1) {
    s1 += __shfl_xor(s1, off);
    s2 += __shfl_xor(s2, off);
  }
  if (lane == 0) { red[wave] = s1; red[8 + wave] = s2; }
  __syncthreads();
  float ts1 = 0.f, ts2 = 0.f;
#pragma unroll
  for (int w = 0; w < 8; ++w) { ts1 += red[w]; ts2 += red[8 + w]; }
  float mu = ts1 * (1.0f / 4096.0f);
  float var = ts2 * (1.0f / 4096.0f) - mu * mu;
  float rstd = rsqrtf(var + 1e-5f);
#pragma unroll
  for (int m = 0; m < 2; ++m)
#pragma unroll
    for (int r = 0; r < 4; ++r) {
      int p = (wm * 2 + m) * 16 + g4 * 4 + r;
      float oln = (ov_[m * 4 + r] - mu) * rstd * ln_w[ch * 64 + p] + ln_b[ch * 64 + p];
      float cn = ct_r[m * 4 + r] + a_r[m * 4 + r] * ftanh(oln);
      float hv = o_r[m * 4 + r] * ftanh(cn);
      Qb[ch * 65 + p] = hv;
      Vb[ch * 65 + p] = cn;
    }
  __syncthreads();
#pragma unroll
  for (int i = 0; i < 2; ++i) {
    int idx = (tid + 512 * i) * 4;
    int c = idx >> 6, p0 = idx & 63;
    f32x4 hv, cvv;
#pragma unroll
    for (int j = 0; j < 4; ++j) {
      hv[j] = Qb[c * 65 + p0 + j];
      cvv[j] = Vb[c * 65 + p0 + j];
    }
    *(f32x4*)&o_h[b * 4096 + idx] = hv;
    *(f32x4*)&o_c[b * 4096 + idx] = cvv;
  }
}

extern "C" void kernel_launch(void* const* d_in, const int* in_sizes, int n_in,
                              void* d_out, int out_size, void* d_ws, size_t ws_size,
                              hipStream_t stream) {
  (void)in_sizes; (void)n_in; (void)out_size;
  const float* input  = (const float*)d_in[0];
  const float* h_cur  = (const float*)d_in[1];
  const float* c_cur  = (const float*)d_in[2];
  const float* ck     = (const float*)d_in[3];
  const float* cv     = (const float*)d_in[4];
  const int*   amask  = (const int*)d_in[5];
  const float* conv_w = (const float*)d_in[6];
  const float* conv_b = (const float*)d_in[7];
  const float* proj_w = (const float*)d_in[8];
  const float* proj_b = (const float*)d_in[9];
  const float* out_w  = (const float*)d_in[10];
  const float* out_b  = (const float*)d_in[11];
  const float* ln_w   = (const float*)d_in[12];
  const float* ln_b   = (const float*)d_in[13];
  const float* pos_w  = (const float*)d_in[14];
  const float* pos_b  = (const float*)d_in[15];

  char* ws = (char*)d_ws;
  short* pk = (short*)ws;  // 1.03 MB
  float* o_h = (float*)d_out;
  float* o_c = o_h + 2097152;
  float* o_k = o_h + 4194304;
  float* o_v = o_h + 20971520;

  pack_w<<<252, 256, 0, stream>>>(conv_w, proj_w, out_w, pk);

  if (ws_size >= (32u << 20)) {
    float* ws_wt = (float*)(ws + (2u << 20));        // 131 KB softmax weights
    float* ws_ct = (float*)(ws + (16u << 20));       // 8 MB ct
    unsigned* ws_oa = (unsigned*)(ws + (24u << 20)); // 8 MB packed o,a
    mid4_k<<<1024, 512, 0, stream>>>(input, h_cur, c_cur, ck, amask,
                                     conv_b, proj_b, pos_w, pos_b,
                                     pk, pk + 368640,
                                     o_k, o_v, ws_wt, ws_ct, ws_oa);
    tail_k<<<512, 512, 0, stream>>>(input, cv, ws_wt, ws_ct, ws_oa,
                                    out_b, ln_w, ln_b, pk + 479232,
                                    o_h, o_c, o_v);
  } else {
    // fallback: proven R3 pipeline (scratch lives in d_out regions)
    kqv_k<<<512, 512, 0, stream>>>(input, proj_b, pos_w, pk + 368640,
                                   o_h, o_k, o_v);
    attn_k<<<4096, 64, 0, stream>>>(ck, cv, amask, pos_w, pos_b, o_h,
                                    o_k, o_v, o_c);
    cell2_k<<<512, 512, 0, stream>>>(input, h_cur, c_cur, o_c,
                                     conv_b, out_b, ln_w, ln_b,
                                     pk, pk + 479232, o_h, o_c);
  }
}